// Round 4
// baseline (240.616 us; speedup 1.0000x reference)
//
#include <hip/hip_runtime.h>
#include <hip/hip_fp16.h>
#include <math.h>

#define B_ 2
#define H_ 8
#define L_ 2048
#define D_ 64
#define BM 16
#define BN 128
#define NJ (L_ / BN)   // 16 tiles
#define L2E 1.4426950408889634f

typedef __attribute__((ext_vector_type(8))) short short8;
typedef __attribute__((ext_vector_type(4))) float f4;

typedef __attribute__((address_space(3))) void lds_void_t;
typedef const __attribute__((address_space(1))) void gbl_void_t;
#define GLL16(gp, lp) __builtin_amdgcn_global_load_lds( \
    (gbl_void_t*)(gp), (lds_void_t*)(lp), 16, 0, 0)

#define MFMA16(a, b, c) __builtin_amdgcn_mfma_f32_16x16x32_bf16(a, b, c, 0, 0, 0)

struct LdsT {
  union {
    struct { short8 kth[BN * 8]; short8 ktl[BN * 8]; } k;  // 32 KB
    float att[16 * 516];                                    // 33 KB store staging
  } u;
  float muv[2][D_];
  float rq0[BM], rq1[BM];
  float red[4][BM];
  float2 ckt[BN];   // fallback col consts
};

__device__ inline void split8(const float4& a0, const float4& a1,
                              short8& hi, short8& lo) {
  float xs[8] = {a0.x, a0.y, a0.z, a0.w, a1.x, a1.y, a1.z, a1.w};
#pragma unroll
  for (int e = 0; e < 8; ++e) {
    unsigned u  = __float_as_uint(xs[e]);
    unsigned hb = (u + 0x8000u) & 0xFFFF0000u;   // RN-ish bf16, residual exact
    float    r  = xs[e] - __uint_as_float(hb);
    unsigned lb = (__float_as_uint(r) + 0x8000u) >> 16;
    hi[e] = (short)(hb >> 16);
    lo[e] = (short)lb;
  }
}

__device__ inline unsigned packh2(float a, float b) {
  __half2 h = __floats2half2_rn(a, b);
  return __builtin_bit_cast(unsigned, h);
}

// Precompute: col consts ck = L2E*(s*|k-mu_c|^2 - neg), and K as pre-swizzled
// bf16 hi/lo groups: wh[(bh*L + c)*8 + g'] = k[c][8*(g'^(c&7)) .. +7] (hi).
__global__ __launch_bounds__(256) void prep_kernel(
    const float* __restrict__ k, const float* __restrict__ mask,
    const float* __restrict__ mu, float2* __restrict__ ck,
    short8* __restrict__ wh, short8* __restrict__ wl)
{
  int bh = blockIdx.x >> 3;
  int c  = (blockIdx.x & 7) * 256 + threadIdx.x;
  int b  = bh >> 3, h = bh & 7;
  const float s = -0.0625f;  // -0.5 / sqrt(64)
  const float* kp  = k  + ((size_t)bh * L_ + c) * D_;
  const float* mu0 = mu + (size_t)h * D_;
  const float* mu1 = mu + (size_t)(H_ * D_) + (size_t)h * D_;
  float x[D_];
#pragma unroll
  for (int d = 0; d < D_; d += 4)
    *reinterpret_cast<float4*>(&x[d]) = *reinterpret_cast<const float4*>(kp + d);
  float s0 = 0.f, s1 = 0.f;
#pragma unroll
  for (int d = 0; d < D_; ++d) {
    float a = x[d] - mu0[d]; s0 += a * a;
    float bb = x[d] - mu1[d]; s1 += bb * bb;
  }
  float neg = 1.0e6f * (1.0f - mask[(size_t)b * L_ + c]);
  ck[(size_t)bh * L_ + c] =
      make_float2((s * s0 - neg) * L2E, (s * s1 - neg) * L2E);
#pragma unroll
  for (int gp = 0; gp < 8; ++gp) {
    int g = gp ^ (c & 7);
    short8 hi, lo;
    split8(*reinterpret_cast<const float4*>(&x[8 * g]),
           *reinterpret_cast<const float4*>(&x[8 * g + 4]), hi, lo);
    size_t idx = ((size_t)bh * L_ + c) * 8 + gp;
    wh[idx] = hi;
    wl[idx] = lo;
  }
}

template <bool USE_WS>
__global__ __launch_bounds__(256, 3) void mg_kernel(
    const float* __restrict__ q, const float* __restrict__ kk,
    const float* __restrict__ mask, const float* __restrict__ mu,
    const float* __restrict__ pi, const float2* __restrict__ ckw,
    const short8* __restrict__ wh, const short8* __restrict__ wl,
    float* __restrict__ out)
{
  extern __shared__ __align__(16) char smem_raw[];
  LdsT& S = *reinterpret_cast<LdsT*>(smem_raw);
  const int t = threadIdx.x;
  int bid = blockIdx.x;
  int vwg = (bid & 7) * 256 + (bid >> 3);   // XCD-chunked, bijective
  int bh  = vwg >> 7;
  int rb  = vwg & 127;
  int b = bh >> 3, h = bh & 7;
  int row0 = rb * BM;

  const int w  = t >> 6;    // wave -> 32-col chunk
  const int ln = t & 63;
  const int ci = ln & 15;   // col within 16 / A-row lane
  const int kg = ln >> 4;   // k-group lane

  const float s   = -0.0625f;
  const float DDC = 0.125f * L2E;   // -2s * log2e

  const float*  maskb = mask + (size_t)b * L_;
  const float2* ckb   = ckw + (size_t)bh * L_;
  const float4* kb4   = (const float4*)(kk + (size_t)bh * L_ * D_);
  const short8* whb   = wh + (size_t)bh * (L_ * 8);
  const short8* wlb   = wl + (size_t)bh * (L_ * 8);

  float pi0 = fminf(fmaxf(pi[0], 0.f), 1.f);
  float pi1 = fminf(fmaxf(pi[1], 0.f), 1.f);
  float lp0 = __log2f(pi0), lp1 = __log2f(pi1);

  if (t < 2 * D_)
    S.muv[t >> 6][t & 63] =
        mu[(size_t)(t >> 6) * (H_ * D_) + (size_t)h * D_ + (t & 63)];

  // A-fragments (Q rows, split bf16)
  short8 ah[2], al[2];
  {
    const float* qrow = q + ((size_t)bh * L_ + row0 + ci) * D_;
#pragma unroll
    for (int h2 = 0; h2 < 2; ++h2) {
      float4 a0 = *reinterpret_cast<const float4*>(qrow + 32 * h2 + kg * 8);
      float4 a1 = *reinterpret_cast<const float4*>(qrow + 32 * h2 + kg * 8 + 4);
      split8(a0, a1, ah[h2], al[h2]);
    }
  }
  __syncthreads();

  // per-row constants rq_c = L2E*(s*q^2 + 2s*(q.mu_c)) + log2(pi_c)
  if (t < BM) {
    const float* qr = q + ((size_t)bh * L_ + row0 + t) * D_;
    float a0 = 0.f, a1 = 0.f, a2 = 0.f;
#pragma unroll
    for (int dq = 0; dq < 16; ++dq) {
      float4 qv = *reinterpret_cast<const float4*>(qr + 4 * dq);
      a0 += qv.x * qv.x + qv.y * qv.y + qv.z * qv.z + qv.w * qv.w;
      a1 += qv.x * S.muv[0][4*dq] + qv.y * S.muv[0][4*dq+1] +
            qv.z * S.muv[0][4*dq+2] + qv.w * S.muv[0][4*dq+3];
      a2 += qv.x * S.muv[1][4*dq] + qv.y * S.muv[1][4*dq+1] +
            qv.z * S.muv[1][4*dq+2] + qv.w * S.muv[1][4*dq+3];
    }
    S.rq0[t] = (s * a0 + 2.f * s * a1) * L2E + lp0;
    S.rq1[t] = (s * a0 + 2.f * s * a2) * L2E + lp1;
  }
  __syncthreads();

  float rq0r[4], rq1r[4];
#pragma unroll
  for (int reg = 0; reg < 4; ++reg) {
    rq0r[reg] = S.rq0[kg * 4 + reg];
    rq1r[reg] = S.rq1[kg * 4 + reg];
  }

  unsigned av2[NJ][2][2];          // fp16-packed unnormalized attn
  float rsum[4] = {0.f, 0.f, 0.f, 0.f};

#pragma unroll
  for (int j = 0; j < NJ; ++j) {
    __syncthreads();   // prev tile's LDS reads done
    float2 cc[2];
    if (USE_WS) {
#pragma unroll
      for (int i = 0; i < 4; ++i)
        GLL16(whb + (size_t)j * (BN * 8) + t + 256 * i, &S.u.k.kth[t + 256 * i]);
#pragma unroll
      for (int i = 0; i < 4; ++i)
        GLL16(wlb + (size_t)j * (BN * 8) + t + 256 * i, &S.u.k.ktl[t + 256 * i]);
#pragma unroll
      for (int n = 0; n < 2; ++n)
        cc[n] = ckb[j * BN + w * 32 + 16 * n + ci];
      __syncthreads();
    } else {
#pragma unroll
      for (int i = 0; i < 4; ++i) {
        int u = t + 256 * i;
        int col = u >> 3, gp = u & 7, g = gp ^ (col & 7);
        float4 x0 = kb4[(size_t)(j * BN + col) * 16 + 2 * g];
        float4 x1 = kb4[(size_t)(j * BN + col) * 16 + 2 * g + 1];
        short8 hi, lo;
        split8(x0, x1, hi, lo);
        S.u.k.kth[u] = hi;
        S.u.k.ktl[u] = lo;
      }
      if (t < BN) {
        const float* kc = kk + ((size_t)bh * L_ + j * BN + t) * D_;
        float s0 = 0.f, s1 = 0.f;
#pragma unroll
        for (int dq = 0; dq < 16; ++dq) {
          float4 kv = *reinterpret_cast<const float4*>(kc + 4 * dq);
          float a;
          a = kv.x - S.muv[0][4*dq];   s0 += a * a;
          a = kv.y - S.muv[0][4*dq+1]; s0 += a * a;
          a = kv.z - S.muv[0][4*dq+2]; s0 += a * a;
          a = kv.w - S.muv[0][4*dq+3]; s0 += a * a;
          a = kv.x - S.muv[1][4*dq];   s1 += a * a;
          a = kv.y - S.muv[1][4*dq+1]; s1 += a * a;
          a = kv.z - S.muv[1][4*dq+2]; s1 += a * a;
          a = kv.w - S.muv[1][4*dq+3]; s1 += a * a;
        }
        float neg = 1.0e6f * (1.0f - maskb[j * BN + t]);
        S.ckt[t] = make_float2((s * s0 - neg) * L2E, (s * s1 - neg) * L2E);
      }
      __syncthreads();
#pragma unroll
      for (int n = 0; n < 2; ++n) cc[n] = S.ckt[w * 32 + 16 * n + ci];
    }

    // 2 col-blocks x 6 MFMA (hi*hi, hi*lo, lo*hi over 2 k-halves)
#pragma unroll
    for (int n = 0; n < 2; ++n) {
      int base = (w * 32 + n * 16 + ci) * 8;
      int x7 = ci & 7;
      short8 b0h = S.u.k.kth[base + (kg ^ x7)];
      short8 b1h = S.u.k.kth[base + ((4 + kg) ^ x7)];
      short8 b0l = S.u.k.ktl[base + (kg ^ x7)];
      short8 b1l = S.u.k.ktl[base + ((4 + kg) ^ x7)];
      f4 acc = {0.f, 0.f, 0.f, 0.f};
      acc = MFMA16(ah[0], b0h, acc);
      acc = MFMA16(ah[1], b1h, acc);
      acc = MFMA16(ah[0], b0l, acc);
      acc = MFMA16(ah[1], b1l, acc);
      acc = MFMA16(al[0], b0h, acc);
      acc = MFMA16(al[1], b1h, acc);
      float aa[4];
#pragma unroll
      for (int reg = 0; reg < 4; ++reg) {
        float dd = DDC * acc[reg];
        float e0 = __builtin_amdgcn_exp2f(rq0r[reg] + cc[n].x + dd);
        float e1 = __builtin_amdgcn_exp2f(rq1r[reg] + cc[n].y + dd);
        float a  = e0 + e1;      // pi folded into rq via log2(pi)
        aa[reg] = a;
        rsum[reg] += a;
      }
      av2[j][n][0] = packh2(aa[0], aa[1]);
      av2[j][n][1] = packh2(aa[2], aa[3]);
    }
  }

  // row sums: reduce over 16 col-lanes, then across 4 waves
#pragma unroll
  for (int reg = 0; reg < 4; ++reg) {
    float v = rsum[reg];
    v += __shfl_xor(v, 1, 64);
    v += __shfl_xor(v, 2, 64);
    v += __shfl_xor(v, 4, 64);
    v += __shfl_xor(v, 8, 64);
    if (ci == 0) S.red[w][kg * 4 + reg] = v;
  }
  __syncthreads();
  float inv[4];
#pragma unroll
  for (int reg = 0; reg < 4; ++reg) {
    int r = kg * 4 + reg;
    inv[reg] = 1.0f / (S.red[0][r] + S.red[1][r] + S.red[2][r] + S.red[3][r]);
  }

  // write-out via LDS transpose (K tiles dead), 4 chunks x 512 cols
  float* ob = out + ((size_t)bh * L_ + row0) * L_;
#pragma unroll
  for (int ch = 0; ch < 4; ++ch) {
    if (ch) __syncthreads();
#pragma unroll
    for (int jj = 0; jj < 4; ++jj) {
      int j = 4 * ch + jj;
#pragma unroll
      for (int n = 0; n < 2; ++n)
#pragma unroll
        for (int p = 0; p < 2; ++p) {
          __half2 hp = __builtin_bit_cast(__half2, av2[j][n][p]);
          float2 f = __half22float2(hp);
          int colx = jj * 128 + w * 32 + n * 16 + ci;
          S.u.att[(kg * 4 + 2 * p) * 516 + colx]     = f.x * inv[2 * p];
          S.u.att[(kg * 4 + 2 * p + 1) * 516 + colx] = f.y * inv[2 * p + 1];
        }
    }
    __syncthreads();
#pragma unroll
    for (int i = 0; i < 8; ++i) {
      int idx = i * 256 + t;
      int row = idx >> 7, c4 = idx & 127;
      float4 v = *reinterpret_cast<const float4*>(&S.u.att[row * 516 + c4 * 4]);
      *reinterpret_cast<float4*>(ob + (size_t)row * L_ + ch * 512 + c4 * 4) = v;
    }
  }
}

extern "C" void kernel_launch(void* const* d_in, const int* in_sizes, int n_in,
                              void* d_out, int out_size, void* d_ws, size_t ws_size,
                              hipStream_t stream) {
  const float* q    = (const float*)d_in[0];
  const float* k    = (const float*)d_in[1];
  const float* mask = (const float*)d_in[2];
  const float* mu   = (const float*)d_in[3];
  const float* pi   = (const float*)d_in[4];
  float* out = (float*)d_out;

  const size_t smem     = sizeof(LdsT);
  const size_t ck_bytes = (size_t)B_ * H_ * L_ * sizeof(float2);       // 256 KB
  const size_t wp_bytes = (size_t)B_ * H_ * L_ * D_ * sizeof(short);   // 4 MB each
  const bool use_ws = (ws_size >= ck_bytes + 2 * wp_bytes) && (d_ws != nullptr);

  if (use_ws) {
    float2* ck = (float2*)d_ws;
    short8* wh = (short8*)((char*)d_ws + ck_bytes);
    short8* wl = (short8*)((char*)d_ws + ck_bytes + wp_bytes);
    (void)hipFuncSetAttribute(reinterpret_cast<const void*>(&mg_kernel<true>),
                              hipFuncAttributeMaxDynamicSharedMemorySize, (int)smem);
    prep_kernel<<<dim3(B_ * H_ * 8), dim3(256), 0, stream>>>(k, mask, mu, ck, wh, wl);
    mg_kernel<true><<<dim3(B_ * H_ * (L_ / BM)), dim3(256), smem, stream>>>(
        q, k, mask, mu, pi, ck, wh, wl, out);
  } else {
    (void)hipFuncSetAttribute(reinterpret_cast<const void*>(&mg_kernel<false>),
                              hipFuncAttributeMaxDynamicSharedMemorySize, (int)smem);
    mg_kernel<false><<<dim3(B_ * H_ * (L_ / BM)), dim3(256), smem, stream>>>(
        q, k, mask, mu, pi, nullptr, nullptr, nullptr, out);
  }
}

// Round 5
// 158.445 us; speedup vs baseline: 1.5186x; 1.5186x over previous
//
#include <hip/hip_runtime.h>
#include <hip/hip_fp16.h>
#include <math.h>

#define B_ 2
#define H_ 8
#define L_ 2048
#define D_ 64
#define BM 16
#define BN 128
#define NJ (L_ / BN)   // 16 tiles
#define L2E 1.4426950408889634f

typedef __attribute__((ext_vector_type(8))) short short8;
typedef __attribute__((ext_vector_type(4))) float f4;

typedef __attribute__((address_space(3))) void lds_void_t;
typedef const __attribute__((address_space(1))) void gbl_void_t;
#define GLL16(gp, lp) __builtin_amdgcn_global_load_lds( \
    (gbl_void_t*)(gp), (lds_void_t*)(lp), 16, 0, 0)

#define MFMA16(a, b, c) __builtin_amdgcn_mfma_f32_16x16x32_bf16(a, b, c, 0, 0, 0)

struct LdsT {
  union {
    struct { short8 kth[BN * 8]; short8 ktl[BN * 8]; } k;  // 32 KB
    float att[16 * 516];                                    // 33 KB store staging
  } u;
  float muv[2][D_];
  float rq0[BM], rq1[BM];
  float red[4][BM];
  float2 ckt[BN];   // fallback col consts
};

__device__ inline void split8(const float4& a0, const float4& a1,
                              short8& hi, short8& lo) {
  float xs[8] = {a0.x, a0.y, a0.z, a0.w, a1.x, a1.y, a1.z, a1.w};
#pragma unroll
  for (int e = 0; e < 8; ++e) {
    unsigned u  = __float_as_uint(xs[e]);
    unsigned hb = (u + 0x8000u) & 0xFFFF0000u;   // RN-ish bf16, residual exact
    float    r  = xs[e] - __uint_as_float(hb);
    unsigned lb = (__float_as_uint(r) + 0x8000u) >> 16;
    hi[e] = (short)(hb >> 16);
    lo[e] = (short)lb;
  }
}

__device__ inline unsigned packh2(float a, float b) {
  __half2 h = __floats2half2_rn(a, b);
  return __builtin_bit_cast(unsigned, h);
}

// Precompute: col consts ck = L2E*(s*|k-mu_c|^2 - neg), and K as pre-swizzled
// bf16 hi/lo groups: wh[(bh*L + c)*8 + g'] = k[c][8*(g'^(c&7)) .. +7] (hi).
__global__ __launch_bounds__(256) void prep_kernel(
    const float* __restrict__ k, const float* __restrict__ mask,
    const float* __restrict__ mu, float2* __restrict__ ck,
    short8* __restrict__ wh, short8* __restrict__ wl)
{
  int bh = blockIdx.x >> 3;
  int c  = (blockIdx.x & 7) * 256 + threadIdx.x;
  int b  = bh >> 3, h = bh & 7;
  const float s = -0.0625f;  // -0.5 / sqrt(64)
  const float* kp  = k  + ((size_t)bh * L_ + c) * D_;
  const float* mu0 = mu + (size_t)h * D_;
  const float* mu1 = mu + (size_t)(H_ * D_) + (size_t)h * D_;
  float x[D_];
#pragma unroll
  for (int d = 0; d < D_; d += 4)
    *reinterpret_cast<float4*>(&x[d]) = *reinterpret_cast<const float4*>(kp + d);
  float s0 = 0.f, s1 = 0.f;
#pragma unroll
  for (int d = 0; d < D_; ++d) {
    float a = x[d] - mu0[d]; s0 += a * a;
    float bb = x[d] - mu1[d]; s1 += bb * bb;
  }
  float neg = 1.0e6f * (1.0f - mask[(size_t)b * L_ + c]);
  ck[(size_t)bh * L_ + c] =
      make_float2((s * s0 - neg) * L2E, (s * s1 - neg) * L2E);
#pragma unroll
  for (int gp = 0; gp < 8; ++gp) {
    int g = gp ^ (c & 7);
    short8 hi, lo;
    split8(*reinterpret_cast<const float4*>(&x[8 * g]),
           *reinterpret_cast<const float4*>(&x[8 * g + 4]), hi, lo);
    size_t idx = ((size_t)bh * L_ + c) * 8 + gp;
    wh[idx] = hi;
    wl[idx] = lo;
  }
}

template <bool USE_WS>
__global__ __launch_bounds__(256, 2) void mg_kernel(
    const float* __restrict__ q, const float* __restrict__ kk,
    const float* __restrict__ mask, const float* __restrict__ mu,
    const float* __restrict__ pi, const float2* __restrict__ ckw,
    const short8* __restrict__ wh, const short8* __restrict__ wl,
    float* __restrict__ out)
{
  extern __shared__ __align__(16) char smem_raw[];
  LdsT& S = *reinterpret_cast<LdsT*>(smem_raw);
  const int t = threadIdx.x;
  int bid = blockIdx.x;
  int vwg = (bid & 7) * 256 + (bid >> 3);   // XCD-chunked, bijective
  int bh  = vwg >> 7;
  int rb  = vwg & 127;
  int b = bh >> 3, h = bh & 7;
  int row0 = rb * BM;

  const int w  = t >> 6;    // wave -> 32-col chunk
  const int ln = t & 63;
  const int ci = ln & 15;   // col within 16 / A-row lane
  const int kg = ln >> 4;   // k-group lane

  const float s   = -0.0625f;
  const float DDC = 0.125f * L2E;   // -2s * log2e

  const float*  maskb = mask + (size_t)b * L_;
  const float2* ckb   = ckw + (size_t)bh * L_;
  const float4* kb4   = (const float4*)(kk + (size_t)bh * L_ * D_);
  const short8* whb   = wh + (size_t)bh * (L_ * 8);
  const short8* wlb   = wl + (size_t)bh * (L_ * 8);

  if (t < 2 * D_)
    S.muv[t >> 6][t & 63] =
        mu[(size_t)(t >> 6) * (H_ * D_) + (size_t)h * D_ + (t & 63)];

  // A-fragments (Q rows, split bf16)
  short8 ah[2], al[2];
  {
    const float* qrow = q + ((size_t)bh * L_ + row0 + ci) * D_;
#pragma unroll
    for (int h2 = 0; h2 < 2; ++h2) {
      float4 a0 = *reinterpret_cast<const float4*>(qrow + 32 * h2 + kg * 8);
      float4 a1 = *reinterpret_cast<const float4*>(qrow + 32 * h2 + kg * 8 + 4);
      split8(a0, a1, ah[h2], al[h2]);
    }
  }
  __syncthreads();

  // per-row constants rq_c = L2E*(s*q^2 + 2s*(q.mu_c)) + log2(pi_c)
  if (t < BM) {
    float pi0 = fminf(fmaxf(pi[0], 0.f), 1.f);
    float pi1 = fminf(fmaxf(pi[1], 0.f), 1.f);
    const float* qr = q + ((size_t)bh * L_ + row0 + t) * D_;
    float a0 = 0.f, a1 = 0.f, a2 = 0.f;
#pragma unroll
    for (int dq = 0; dq < 16; ++dq) {
      float4 qv = *reinterpret_cast<const float4*>(qr + 4 * dq);
      a0 += qv.x * qv.x + qv.y * qv.y + qv.z * qv.z + qv.w * qv.w;
      a1 += qv.x * S.muv[0][4*dq] + qv.y * S.muv[0][4*dq+1] +
            qv.z * S.muv[0][4*dq+2] + qv.w * S.muv[0][4*dq+3];
      a2 += qv.x * S.muv[1][4*dq] + qv.y * S.muv[1][4*dq+1] +
            qv.z * S.muv[1][4*dq+2] + qv.w * S.muv[1][4*dq+3];
    }
    S.rq0[t] = (s * a0 + 2.f * s * a1) * L2E + __log2f(pi0);
    S.rq1[t] = (s * a0 + 2.f * s * a2) * L2E + __log2f(pi1);
  }
  __syncthreads();

  float rq0r[4], rq1r[4];
#pragma unroll
  for (int reg = 0; reg < 4; ++reg) {
    rq0r[reg] = S.rq0[kg * 4 + reg];
    rq1r[reg] = S.rq1[kg * 4 + reg];
  }

  uint4 av2[NJ];          // fp16-packed unnormalized attn (64 VGPRs)
  float rsum[4] = {0.f, 0.f, 0.f, 0.f};

#pragma unroll
  for (int j = 0; j < NJ; ++j) {
    __syncthreads();   // prev tile's LDS reads done
    float2 cc[2];
    if (USE_WS) {
#pragma unroll
      for (int i = 0; i < 4; ++i)
        GLL16(whb + (size_t)j * (BN * 8) + t + 256 * i, &S.u.k.kth[t + 256 * i]);
#pragma unroll
      for (int i = 0; i < 4; ++i)
        GLL16(wlb + (size_t)j * (BN * 8) + t + 256 * i, &S.u.k.ktl[t + 256 * i]);
#pragma unroll
      for (int n = 0; n < 2; ++n)
        cc[n] = ckb[j * BN + w * 32 + 16 * n + ci];
      __syncthreads();
    } else {
#pragma unroll
      for (int i = 0; i < 4; ++i) {
        int u = t + 256 * i;
        int col = u >> 3, gp = u & 7, g = gp ^ (col & 7);
        float4 x0 = kb4[(size_t)(j * BN + col) * 16 + 2 * g];
        float4 x1 = kb4[(size_t)(j * BN + col) * 16 + 2 * g + 1];
        short8 hi, lo;
        split8(x0, x1, hi, lo);
        S.u.k.kth[u] = hi;
        S.u.k.ktl[u] = lo;
      }
      if (t < BN) {
        const float* kc = kk + ((size_t)bh * L_ + j * BN + t) * D_;
        float s0 = 0.f, s1 = 0.f;
#pragma unroll
        for (int dq = 0; dq < 16; ++dq) {
          float4 kv = *reinterpret_cast<const float4*>(kc + 4 * dq);
          float a;
          a = kv.x - S.muv[0][4*dq];   s0 += a * a;
          a = kv.y - S.muv[0][4*dq+1]; s0 += a * a;
          a = kv.z - S.muv[0][4*dq+2]; s0 += a * a;
          a = kv.w - S.muv[0][4*dq+3]; s0 += a * a;
          a = kv.x - S.muv[1][4*dq];   s1 += a * a;
          a = kv.y - S.muv[1][4*dq+1]; s1 += a * a;
          a = kv.z - S.muv[1][4*dq+2]; s1 += a * a;
          a = kv.w - S.muv[1][4*dq+3]; s1 += a * a;
        }
        float neg = 1.0e6f * (1.0f - maskb[j * BN + t]);
        S.ckt[t] = make_float2((s * s0 - neg) * L2E, (s * s1 - neg) * L2E);
      }
      __syncthreads();
#pragma unroll
      for (int n = 0; n < 2; ++n) cc[n] = S.ckt[w * 32 + 16 * n + ci];
    }

    // 2 col-blocks x 6 MFMA (hi*hi, hi*lo, lo*hi over 2 k-halves)
    uint4 cur;
#pragma unroll
    for (int n = 0; n < 2; ++n) {
      int base = (w * 32 + n * 16 + ci) * 8;
      int x7 = ci & 7;
      short8 b0h = S.u.k.kth[base + (kg ^ x7)];
      short8 b1h = S.u.k.kth[base + ((4 + kg) ^ x7)];
      short8 b0l = S.u.k.ktl[base + (kg ^ x7)];
      short8 b1l = S.u.k.ktl[base + ((4 + kg) ^ x7)];
      f4 acc = {0.f, 0.f, 0.f, 0.f};
      acc = MFMA16(ah[0], b0h, acc);
      acc = MFMA16(ah[1], b1h, acc);
      acc = MFMA16(ah[0], b0l, acc);
      acc = MFMA16(ah[1], b1l, acc);
      acc = MFMA16(al[0], b0h, acc);
      acc = MFMA16(al[1], b1h, acc);
      float aa[4];
#pragma unroll
      for (int reg = 0; reg < 4; ++reg) {
        float dd = DDC * acc[reg];
        float e0 = __builtin_amdgcn_exp2f(rq0r[reg] + cc[n].x + dd);
        float e1 = __builtin_amdgcn_exp2f(rq1r[reg] + cc[n].y + dd);
        float a  = e0 + e1;      // pi folded into rq via log2(pi)
        aa[reg] = a;
        rsum[reg] += a;
      }
      if (n == 0) {
        cur.x = packh2(aa[0], aa[1]);
        cur.y = packh2(aa[2], aa[3]);
      } else {
        cur.z = packh2(aa[0], aa[1]);
        cur.w = packh2(aa[2], aa[3]);
      }
    }
    av2[j] = cur;
  }

  // row sums: reduce over 16 col-lanes, then across 4 waves
#pragma unroll
  for (int reg = 0; reg < 4; ++reg) {
    float v = rsum[reg];
    v += __shfl_xor(v, 1, 64);
    v += __shfl_xor(v, 2, 64);
    v += __shfl_xor(v, 4, 64);
    v += __shfl_xor(v, 8, 64);
    if (ci == 0) S.red[w][kg * 4 + reg] = v;
  }
  __syncthreads();
  float inv[4];
#pragma unroll
  for (int reg = 0; reg < 4; ++reg) {
    int r = kg * 4 + reg;
    inv[reg] = 1.0f / (S.red[0][r] + S.red[1][r] + S.red[2][r] + S.red[3][r]);
  }

  // write-out via LDS transpose (K tiles dead), 4 chunks x 512 cols
  float* ob = out + ((size_t)bh * L_ + row0) * L_;
#pragma unroll
  for (int ch = 0; ch < 4; ++ch) {
    if (ch) __syncthreads();
#pragma unroll
    for (int jj = 0; jj < 4; ++jj) {
      uint4 v = av2[4 * ch + jj];
      unsigned comps[4] = {v.x, v.y, v.z, v.w};
#pragma unroll
      for (int n = 0; n < 2; ++n)
#pragma unroll
        for (int p = 0; p < 2; ++p) {
          __half2 hp = __builtin_bit_cast(__half2, comps[2 * n + p]);
          float2 f = __half22float2(hp);
          int colx = jj * 128 + w * 32 + n * 16 + ci;
          S.u.att[(kg * 4 + 2 * p) * 516 + colx]     = f.x * inv[2 * p];
          S.u.att[(kg * 4 + 2 * p + 1) * 516 + colx] = f.y * inv[2 * p + 1];
        }
    }
    __syncthreads();
#pragma unroll
    for (int i = 0; i < 8; ++i) {
      int idx = i * 256 + t;
      int row = idx >> 7, c4 = idx & 127;
      float4 v = *reinterpret_cast<const float4*>(&S.u.att[row * 516 + c4 * 4]);
      *reinterpret_cast<float4*>(ob + (size_t)row * L_ + ch * 512 + c4 * 4) = v;
    }
  }
}

extern "C" void kernel_launch(void* const* d_in, const int* in_sizes, int n_in,
                              void* d_out, int out_size, void* d_ws, size_t ws_size,
                              hipStream_t stream) {
  const float* q    = (const float*)d_in[0];
  const float* k    = (const float*)d_in[1];
  const float* mask = (const float*)d_in[2];
  const float* mu   = (const float*)d_in[3];
  const float* pi   = (const float*)d_in[4];
  float* out = (float*)d_out;

  const size_t smem     = sizeof(LdsT);
  const size_t ck_bytes = (size_t)B_ * H_ * L_ * sizeof(float2);       // 256 KB
  const size_t wp_bytes = (size_t)B_ * H_ * L_ * D_ * sizeof(short);   // 4 MB each
  const bool use_ws = (ws_size >= ck_bytes + 2 * wp_bytes) && (d_ws != nullptr);

  if (use_ws) {
    float2* ck = (float2*)d_ws;
    short8* wh = (short8*)((char*)d_ws + ck_bytes);
    short8* wl = (short8*)((char*)d_ws + ck_bytes + wp_bytes);
    (void)hipFuncSetAttribute(reinterpret_cast<const void*>(&mg_kernel<true>),
                              hipFuncAttributeMaxDynamicSharedMemorySize, (int)smem);
    prep_kernel<<<dim3(B_ * H_ * 8), dim3(256), 0, stream>>>(k, mask, mu, ck, wh, wl);
    mg_kernel<true><<<dim3(B_ * H_ * (L_ / BM)), dim3(256), smem, stream>>>(
        q, k, mask, mu, pi, ck, wh, wl, out);
  } else {
    (void)hipFuncSetAttribute(reinterpret_cast<const void*>(&mg_kernel<false>),
                              hipFuncAttributeMaxDynamicSharedMemorySize, (int)smem);
    mg_kernel<false><<<dim3(B_ * H_ * (L_ / BM)), dim3(256), smem, stream>>>(
        q, k, mask, mu, pi, nullptr, nullptr, nullptr, out);
  }
}

// Round 6
// 141.638 us; speedup vs baseline: 1.6988x; 1.1187x over previous
//
#include <hip/hip_runtime.h>
#include <math.h>

#define B_ 2
#define H_ 8
#define L_ 2048
#define D_ 64
#define BM 16
#define BN 128
#define NJ (L_ / BN)   // 16 tiles
#define L2E 1.4426950408889634f

typedef __attribute__((ext_vector_type(8))) short short8;
typedef __attribute__((ext_vector_type(4))) float f4;

typedef __attribute__((address_space(3))) void lds_void_t;
typedef const __attribute__((address_space(1))) void gbl_void_t;
#define GLL16(gp, lp) __builtin_amdgcn_global_load_lds( \
    (gbl_void_t*)(gp), (lds_void_t*)(lp), 16, 0, 0)

#define MFMA16(a, b, c) __builtin_amdgcn_mfma_f32_16x16x32_bf16(a, b, c, 0, 0, 0)

struct LdsT {
  short8 kth[BN * 8];   // 16 KB  idx = col*8 + (slot ^ (col&7))
  short8 ktl[BN * 8];   // 16 KB
  float  muv[2][D_];
  float  er0[BM], er1[BM];   // pi_c * exp2(rq_c) per row
  float  red[4][BM];
  float2 ckt[BN];            // fallback col factors (exp2'd)
};

__device__ inline void split8(const float4& a0, const float4& a1,
                              short8& hi, short8& lo) {
  float xs[8] = {a0.x, a0.y, a0.z, a0.w, a1.x, a1.y, a1.z, a1.w};
#pragma unroll
  for (int e = 0; e < 8; ++e) {
    unsigned u  = __float_as_uint(xs[e]);
    unsigned hb = (u + 0x8000u) & 0xFFFF0000u;   // RN-ish bf16, residual exact
    float    r  = xs[e] - __uint_as_float(hb);
    unsigned lb = (__float_as_uint(r) + 0x8000u) >> 16;
    hi[e] = (short)(hb >> 16);
    lo[e] = (short)lb;
  }
}

// Precompute: col factors ec_c = exp2(L2E*(s*|k-mu_c|^2 - neg)), and K as
// pre-swizzled bf16 hi/lo: wh[(bh*L+c)*8+g'] = k[c][8*(g'^(c&7))..+7] (hi).
__global__ __launch_bounds__(256) void prep_kernel(
    const float* __restrict__ k, const float* __restrict__ mask,
    const float* __restrict__ mu, float2* __restrict__ ck,
    short8* __restrict__ wh, short8* __restrict__ wl)
{
  int bh = blockIdx.x >> 3;
  int c  = (blockIdx.x & 7) * 256 + threadIdx.x;
  int b  = bh >> 3, h = bh & 7;
  const float s = -0.0625f;  // -0.5 / sqrt(64)
  const float* kp  = k  + ((size_t)bh * L_ + c) * D_;
  const float* mu0 = mu + (size_t)h * D_;
  const float* mu1 = mu + (size_t)(H_ * D_) + (size_t)h * D_;
  float x[D_];
#pragma unroll
  for (int d = 0; d < D_; d += 4)
    *reinterpret_cast<float4*>(&x[d]) = *reinterpret_cast<const float4*>(kp + d);
  float s0 = 0.f, s1 = 0.f;
#pragma unroll
  for (int d = 0; d < D_; ++d) {
    float a = x[d] - mu0[d]; s0 += a * a;
    float bb = x[d] - mu1[d]; s1 += bb * bb;
  }
  float neg = 1.0e6f * (1.0f - mask[(size_t)b * L_ + c]);
  ck[(size_t)bh * L_ + c] = make_float2(exp2f((s * s0 - neg) * L2E),
                                        exp2f((s * s1 - neg) * L2E));
#pragma unroll
  for (int gp = 0; gp < 8; ++gp) {
    int g = gp ^ (c & 7);
    short8 hi, lo;
    split8(*reinterpret_cast<const float4*>(&x[8 * g]),
           *reinterpret_cast<const float4*>(&x[8 * g + 4]), hi, lo);
    size_t idx = ((size_t)bh * L_ + c) * 8 + gp;
    wh[idx] = hi;
    wl[idx] = lo;
  }
}

template <bool USE_WS>
__global__ __launch_bounds__(256, 4) void mg_kernel(
    const float* __restrict__ q, const float* __restrict__ kk,
    const float* __restrict__ mask, const float* __restrict__ mu,
    const float* __restrict__ pi, const float2* __restrict__ ckw,
    const short8* __restrict__ wh, const short8* __restrict__ wl,
    float* __restrict__ out)
{
  extern __shared__ __align__(16) char smem_raw[];
  LdsT& S = *reinterpret_cast<LdsT*>(smem_raw);
  const int t = threadIdx.x;
  int bid = blockIdx.x;
  int vwg = (bid & 7) * 256 + (bid >> 3);   // XCD-chunked, bijective
  int bh  = vwg >> 7;
  int rb  = vwg & 127;
  int b = bh >> 3, h = bh & 7;
  int row0 = rb * BM;

  const int w  = t >> 6;    // wave -> 32-col chunk
  const int ln = t & 63;
  const int ci = ln & 15;   // col lane / A-row lane
  const int kg = ln >> 4;   // k-group lane
  const int x7 = ci & 7;

  const float s   = -0.0625f;
  const float DDC = 0.125f * L2E;   // -2s * log2e

  const float*  maskb = mask + (size_t)b * L_;
  const float2* ckb   = ckw + (size_t)bh * L_;
  const float4* kb4   = (const float4*)(kk + (size_t)bh * L_ * D_);
  const short8* whb   = wh + (size_t)bh * (L_ * 8);
  const short8* wlb   = wl + (size_t)bh * (L_ * 8);

  if (t < 2 * D_)
    S.muv[t >> 6][t & 63] =
        mu[(size_t)(t >> 6) * (H_ * D_) + (size_t)h * D_ + (t & 63)];

  // A-fragments (Q rows, split bf16)
  short8 ah[2], al[2];
  {
    const float* qrow = q + ((size_t)bh * L_ + row0 + ci) * D_;
#pragma unroll
    for (int h2 = 0; h2 < 2; ++h2) {
      float4 a0 = *reinterpret_cast<const float4*>(qrow + 32 * h2 + kg * 8);
      float4 a1 = *reinterpret_cast<const float4*>(qrow + 32 * h2 + kg * 8 + 4);
      split8(a0, a1, ah[h2], al[h2]);
    }
  }
  __syncthreads();

  // per-row factors er_c = pi_c * exp2(L2E*(s*q^2 + 2s*(q.mu_c)))
  if (t < BM) {
    float pi0 = fminf(fmaxf(pi[0], 0.f), 1.f);
    float pi1 = fminf(fmaxf(pi[1], 0.f), 1.f);
    const float* qr = q + ((size_t)bh * L_ + row0 + t) * D_;
    float a0 = 0.f, a1 = 0.f, a2 = 0.f;
#pragma unroll
    for (int dq = 0; dq < 16; ++dq) {
      float4 qv = *reinterpret_cast<const float4*>(qr + 4 * dq);
      a0 += qv.x * qv.x + qv.y * qv.y + qv.z * qv.z + qv.w * qv.w;
      a1 += qv.x * S.muv[0][4*dq] + qv.y * S.muv[0][4*dq+1] +
            qv.z * S.muv[0][4*dq+2] + qv.w * S.muv[0][4*dq+3];
      a2 += qv.x * S.muv[1][4*dq] + qv.y * S.muv[1][4*dq+1] +
            qv.z * S.muv[1][4*dq+2] + qv.w * S.muv[1][4*dq+3];
    }
    S.er0[t] = pi0 * exp2f((s * a0 + 2.f * s * a1) * L2E);
    S.er1[t] = pi1 * exp2f((s * a0 + 2.f * s * a2) * L2E);
  }
  __syncthreads();

  float e0r[4], e1r[4];
#pragma unroll
  for (int reg = 0; reg < 4; ++reg) {
    e0r[reg] = S.er0[kg * 4 + reg];
    e1r[reg] = S.er1[kg * 4 + reg];
  }

  // ---------------- PASS A: row sums only (no stores, no row state) --------
  float rsum[4] = {0.f, 0.f, 0.f, 0.f};
#pragma unroll 1
  for (int j = 0; j < NJ; ++j) {
    __syncthreads();
    float2 ec[2];
    if (USE_WS) {
#pragma unroll
      for (int i = 0; i < 4; ++i)
        GLL16(whb + (size_t)j * (BN * 8) + t + 256 * i, &S.kth[t + 256 * i]);
#pragma unroll
      for (int i = 0; i < 4; ++i)
        GLL16(wlb + (size_t)j * (BN * 8) + t + 256 * i, &S.ktl[t + 256 * i]);
#pragma unroll
      for (int n = 0; n < 2; ++n)
        ec[n] = ckb[j * BN + w * 32 + 16 * n + ci];
      __syncthreads();
    } else {
#pragma unroll
      for (int i = 0; i < 4; ++i) {
        int u = t + 256 * i;
        int col = u >> 3, gp = u & 7, g = gp ^ (col & 7);
        float4 x0 = kb4[(size_t)(j * BN + col) * 16 + 2 * g];
        float4 x1 = kb4[(size_t)(j * BN + col) * 16 + 2 * g + 1];
        short8 hi, lo;
        split8(x0, x1, hi, lo);
        S.kth[u] = hi;
        S.ktl[u] = lo;
      }
      if (t < BN) {
        const float* kc = kk + ((size_t)bh * L_ + j * BN + t) * D_;
        float s0 = 0.f, s1 = 0.f;
#pragma unroll
        for (int dq = 0; dq < 16; ++dq) {
          float4 kv = *reinterpret_cast<const float4*>(kc + 4 * dq);
          float a;
          a = kv.x - S.muv[0][4*dq];   s0 += a * a;
          a = kv.y - S.muv[0][4*dq+1]; s0 += a * a;
          a = kv.z - S.muv[0][4*dq+2]; s0 += a * a;
          a = kv.w - S.muv[0][4*dq+3]; s0 += a * a;
          a = kv.x - S.muv[1][4*dq];   s1 += a * a;
          a = kv.y - S.muv[1][4*dq+1]; s1 += a * a;
          a = kv.z - S.muv[1][4*dq+2]; s1 += a * a;
          a = kv.w - S.muv[1][4*dq+3]; s1 += a * a;
        }
        float neg = 1.0e6f * (1.0f - maskb[j * BN + t]);
        S.ckt[t] = make_float2(exp2f((s * s0 - neg) * L2E),
                               exp2f((s * s1 - neg) * L2E));
      }
      __syncthreads();
#pragma unroll
      for (int n = 0; n < 2; ++n) ec[n] = S.ckt[w * 32 + 16 * n + ci];
    }

#pragma unroll
    for (int n = 0; n < 2; ++n) {
      int base = (w * 32 + n * 16 + ci) * 8;
      short8 b0h = S.kth[base + (kg ^ x7)];
      short8 b1h = S.kth[base + ((4 + kg) ^ x7)];
      short8 b0l = S.ktl[base + (kg ^ x7)];
      short8 b1l = S.ktl[base + ((4 + kg) ^ x7)];
      f4 acc = {0.f, 0.f, 0.f, 0.f};
      acc = MFMA16(ah[0], b0h, acc);
      acc = MFMA16(ah[1], b1h, acc);
      acc = MFMA16(ah[0], b0l, acc);
      acc = MFMA16(ah[1], b1l, acc);
      acc = MFMA16(al[0], b0h, acc);
      acc = MFMA16(al[1], b1h, acc);
#pragma unroll
      for (int reg = 0; reg < 4; ++reg) {
        float g2 = __builtin_amdgcn_exp2f(DDC * acc[reg]);
        float m  = fmaf(e0r[reg], ec[n].x, e1r[reg] * ec[n].y);
        rsum[reg] = fmaf(g2, m, rsum[reg]);
      }
    }
  }

  // row-sum reduce: 16 col-lanes, then 4 waves; fold inv into row factors
#pragma unroll
  for (int reg = 0; reg < 4; ++reg) {
    float v = rsum[reg];
    v += __shfl_xor(v, 1, 64);
    v += __shfl_xor(v, 2, 64);
    v += __shfl_xor(v, 4, 64);
    v += __shfl_xor(v, 8, 64);
    if (ci == 0) S.red[w][kg * 4 + reg] = v;
  }
  __syncthreads();
#pragma unroll
  for (int reg = 0; reg < 4; ++reg) {
    int r = kg * 4 + reg;
    float inv = 1.0f / (S.red[0][r] + S.red[1][r] + S.red[2][r] + S.red[3][r]);
    e0r[reg] *= inv;
    e1r[reg] *= inv;
  }

  // ---------------- PASS B: recompute + direct normalized store ------------
  // Descending j: tile NJ-1 is still resident in LDS from pass A.
  float* obr = out + ((size_t)bh * L_ + row0 + kg * 4) * L_ + w * 32 + ci;
#pragma unroll 1
  for (int jj = 0; jj < NJ; ++jj) {
    const int j = NJ - 1 - jj;
    float2 ec[2];
    if (jj != 0) {
      __syncthreads();
      if (USE_WS) {
#pragma unroll
        for (int i = 0; i < 4; ++i)
          GLL16(whb + (size_t)j * (BN * 8) + t + 256 * i, &S.kth[t + 256 * i]);
#pragma unroll
        for (int i = 0; i < 4; ++i)
          GLL16(wlb + (size_t)j * (BN * 8) + t + 256 * i, &S.ktl[t + 256 * i]);
#pragma unroll
        for (int n = 0; n < 2; ++n)
          ec[n] = ckb[j * BN + w * 32 + 16 * n + ci];
        __syncthreads();
      } else {
#pragma unroll
        for (int i = 0; i < 4; ++i) {
          int u = t + 256 * i;
          int col = u >> 3, gp = u & 7, g = gp ^ (col & 7);
          float4 x0 = kb4[(size_t)(j * BN + col) * 16 + 2 * g];
          float4 x1 = kb4[(size_t)(j * BN + col) * 16 + 2 * g + 1];
          short8 hi, lo;
          split8(x0, x1, hi, lo);
          S.kth[u] = hi;
          S.ktl[u] = lo;
        }
        if (t < BN) {
          const float* kc = kk + ((size_t)bh * L_ + j * BN + t) * D_;
          float s0 = 0.f, s1 = 0.f;
#pragma unroll
          for (int dq = 0; dq < 16; ++dq) {
            float4 kv = *reinterpret_cast<const float4*>(kc + 4 * dq);
            float a;
            a = kv.x - S.muv[0][4*dq];   s0 += a * a;
            a = kv.y - S.muv[0][4*dq+1]; s0 += a * a;
            a = kv.z - S.muv[0][4*dq+2]; s0 += a * a;
            a = kv.w - S.muv[0][4*dq+3]; s0 += a * a;
            a = kv.x - S.muv[1][4*dq];   s1 += a * a;
            a = kv.y - S.muv[1][4*dq+1]; s1 += a * a;
            a = kv.z - S.muv[1][4*dq+2]; s1 += a * a;
            a = kv.w - S.muv[1][4*dq+3]; s1 += a * a;
          }
          float neg = 1.0e6f * (1.0f - maskb[j * BN + t]);
          S.ckt[t] = make_float2(exp2f((s * s0 - neg) * L2E),
                                 exp2f((s * s1 - neg) * L2E));
        }
        __syncthreads();
#pragma unroll
        for (int n = 0; n < 2; ++n) ec[n] = S.ckt[w * 32 + 16 * n + ci];
      }
    } else {
      if (USE_WS) {
#pragma unroll
        for (int n = 0; n < 2; ++n)
          ec[n] = ckb[j * BN + w * 32 + 16 * n + ci];
      } else {
#pragma unroll
        for (int n = 0; n < 2; ++n) ec[n] = S.ckt[w * 32 + 16 * n + ci];
      }
    }

#pragma unroll
    for (int n = 0; n < 2; ++n) {
      int base = (w * 32 + n * 16 + ci) * 8;
      short8 b0h = S.kth[base + (kg ^ x7)];
      short8 b1h = S.kth[base + ((4 + kg) ^ x7)];
      short8 b0l = S.ktl[base + (kg ^ x7)];
      short8 b1l = S.ktl[base + ((4 + kg) ^ x7)];
      f4 acc = {0.f, 0.f, 0.f, 0.f};
      acc = MFMA16(ah[0], b0h, acc);
      acc = MFMA16(ah[1], b1h, acc);
      acc = MFMA16(ah[0], b0l, acc);
      acc = MFMA16(ah[1], b1l, acc);
      acc = MFMA16(al[0], b0h, acc);
      acc = MFMA16(al[1], b1h, acc);
#pragma unroll
      for (int reg = 0; reg < 4; ++reg) {
        float g2 = __builtin_amdgcn_exp2f(DDC * acc[reg]);
        float m  = fmaf(e0r[reg], ec[n].x, e1r[reg] * ec[n].y);
        float p  = g2 * m;
        __builtin_nontemporal_store(
            p, obr + (size_t)reg * L_ + (j * BN + n * 16));
      }
    }
  }
}

extern "C" void kernel_launch(void* const* d_in, const int* in_sizes, int n_in,
                              void* d_out, int out_size, void* d_ws, size_t ws_size,
                              hipStream_t stream) {
  const float* q    = (const float*)d_in[0];
  const float* k    = (const float*)d_in[1];
  const float* mask = (const float*)d_in[2];
  const float* mu   = (const float*)d_in[3];
  const float* pi   = (const float*)d_in[4];
  float* out = (float*)d_out;

  const size_t smem     = sizeof(LdsT);
  const size_t ck_bytes = (size_t)B_ * H_ * L_ * sizeof(float2);       // 256 KB
  const size_t wp_bytes = (size_t)B_ * H_ * L_ * D_ * sizeof(short);   // 4 MB each
  const bool use_ws = (ws_size >= ck_bytes + 2 * wp_bytes) && (d_ws != nullptr);

  if (use_ws) {
    float2* ck = (float2*)d_ws;
    short8* wh = (short8*)((char*)d_ws + ck_bytes);
    short8* wl = (short8*)((char*)d_ws + ck_bytes + wp_bytes);
    (void)hipFuncSetAttribute(reinterpret_cast<const void*>(&mg_kernel<true>),
                              hipFuncAttributeMaxDynamicSharedMemorySize, (int)smem);
    prep_kernel<<<dim3(B_ * H_ * 8), dim3(256), 0, stream>>>(k, mask, mu, ck, wh, wl);
    mg_kernel<true><<<dim3(B_ * H_ * (L_ / BM)), dim3(256), smem, stream>>>(
        q, k, mask, mu, pi, ck, wh, wl, out);
  } else {
    (void)hipFuncSetAttribute(reinterpret_cast<const void*>(&mg_kernel<false>),
                              hipFuncAttributeMaxDynamicSharedMemorySize, (int)smem);
    mg_kernel<false><<<dim3(B_ * H_ * (L_ / BM)), dim3(256), smem, stream>>>(
        q, k, mask, mu, pi, nullptr, nullptr, nullptr, out);
  }
}

// Round 7
// 122.677 us; speedup vs baseline: 1.9614x; 1.1546x over previous
//
#include <hip/hip_runtime.h>
#include <math.h>

#define B_ 2
#define H_ 8
#define L_ 2048
#define D_ 64
#define BM 32          // rows per WG (2 row-blocks of 16 per wave)
#define BN 128
#define NJ (L_ / BN)   // 16 tiles
#define L2E 1.4426950408889634f

typedef __attribute__((ext_vector_type(8))) short short8;
typedef __attribute__((ext_vector_type(4))) float f4;

typedef __attribute__((address_space(3))) void lds_void_t;
typedef const __attribute__((address_space(1))) void gbl_void_t;
#define GLL16(gp, lp) __builtin_amdgcn_global_load_lds( \
    (gbl_void_t*)(gp), (lds_void_t*)(lp), 16, 0, 0)

#define MFMA16(a, b, c) __builtin_amdgcn_mfma_f32_16x16x32_bf16(a, b, c, 0, 0, 0)

struct LdsT {
  short8 kth[BN * 8];   // 16 KB  idx = col*8 + (slot ^ (col&7))
  short8 ktl[BN * 8];   // 16 KB
  float  muv[2][D_];
  float  er0[BM], er1[BM];   // pi_c * exp2(rq_c) per row
  float  red[4][BM];
  float2 ckt[BN];            // fallback col factors (exp2'd)
};

__device__ inline void split8(const float4& a0, const float4& a1,
                              short8& hi, short8& lo) {
  float xs[8] = {a0.x, a0.y, a0.z, a0.w, a1.x, a1.y, a1.z, a1.w};
#pragma unroll
  for (int e = 0; e < 8; ++e) {
    unsigned u  = __float_as_uint(xs[e]);
    unsigned hb = (u + 0x8000u) & 0xFFFF0000u;   // RN-ish bf16, residual exact
    float    r  = xs[e] - __uint_as_float(hb);
    unsigned lb = (__float_as_uint(r) + 0x8000u) >> 16;
    hi[e] = (short)(hb >> 16);
    lo[e] = (short)lb;
  }
}

// Precompute: col factors ec_c = exp2(L2E*(s*|k-mu_c|^2 - neg)), and K as
// pre-swizzled bf16 hi/lo: wh[(bh*L+c)*8+g'] = k[c][8*(g'^(c&7))..+7] (hi).
__global__ __launch_bounds__(256) void prep_kernel(
    const float* __restrict__ k, const float* __restrict__ mask,
    const float* __restrict__ mu, float2* __restrict__ ck,
    short8* __restrict__ wh, short8* __restrict__ wl)
{
  int bh = blockIdx.x >> 3;
  int c  = (blockIdx.x & 7) * 256 + threadIdx.x;
  int b  = bh >> 3, h = bh & 7;
  const float s = -0.0625f;  // -0.5 / sqrt(64)
  const float* kp  = k  + ((size_t)bh * L_ + c) * D_;
  const float* mu0 = mu + (size_t)h * D_;
  const float* mu1 = mu + (size_t)(H_ * D_) + (size_t)h * D_;
  float x[D_];
#pragma unroll
  for (int d = 0; d < D_; d += 4)
    *reinterpret_cast<float4*>(&x[d]) = *reinterpret_cast<const float4*>(kp + d);
  float s0 = 0.f, s1 = 0.f;
#pragma unroll
  for (int d = 0; d < D_; ++d) {
    float a = x[d] - mu0[d]; s0 += a * a;
    float bb = x[d] - mu1[d]; s1 += bb * bb;
  }
  float neg = 1.0e6f * (1.0f - mask[(size_t)b * L_ + c]);
  ck[(size_t)bh * L_ + c] = make_float2(exp2f((s * s0 - neg) * L2E),
                                        exp2f((s * s1 - neg) * L2E));
#pragma unroll
  for (int gp = 0; gp < 8; ++gp) {
    int g = gp ^ (c & 7);
    short8 hi, lo;
    split8(*reinterpret_cast<const float4*>(&x[8 * g]),
           *reinterpret_cast<const float4*>(&x[8 * g + 4]), hi, lo);
    size_t idx = ((size_t)bh * L_ + c) * 8 + gp;
    wh[idx] = hi;
    wl[idx] = lo;
  }
}

template <bool USE_WS>
__global__ __launch_bounds__(256, 4) void mg_kernel(
    const float* __restrict__ q, const float* __restrict__ kk,
    const float* __restrict__ mask, const float* __restrict__ mu,
    const float* __restrict__ pi, const float2* __restrict__ ckw,
    const short8* __restrict__ wh, const short8* __restrict__ wl,
    float* __restrict__ out)
{
  extern __shared__ __align__(16) char smem_raw[];
  LdsT& S = *reinterpret_cast<LdsT*>(smem_raw);
  const int t = threadIdx.x;
  int bid = blockIdx.x;
  int vwg = (bid & 7) * 128 + (bid >> 3);   // XCD-chunked, bijective (1024%8==0)
  int bh  = vwg >> 6;
  int rb  = vwg & 63;
  int b = bh >> 3, h = bh & 7;
  int row0 = rb * BM;

  const int w  = t >> 6;    // wave -> 32-col chunk
  const int ln = t & 63;
  const int ci = ln & 15;   // col lane / A-row lane
  const int kg = ln >> 4;   // k-group lane
  const int x7 = ci & 7;

  const float s   = -0.0625f;
  const float DDC = 0.125f * L2E;   // -2s * log2e

  const float*  maskb = mask + (size_t)b * L_;
  const float2* ckb   = ckw + (size_t)bh * L_;
  const float4* kb4   = (const float4*)(kk + (size_t)bh * L_ * D_);
  const short8* whb   = wh + (size_t)bh * (L_ * 8);
  const short8* wlb   = wl + (size_t)bh * (L_ * 8);

  if (t < 2 * D_)
    S.muv[t >> 6][t & 63] =
        mu[(size_t)(t >> 6) * (H_ * D_) + (size_t)h * D_ + (t & 63)];

  // A-fragments: 2 row-blocks of 16 rows each (split bf16)
  short8 ah[2][2], al[2][2];
#pragma unroll
  for (int rk = 0; rk < 2; ++rk) {
    const float* qrow = q + ((size_t)bh * L_ + row0 + rk * 16 + ci) * D_;
#pragma unroll
    for (int h2 = 0; h2 < 2; ++h2) {
      float4 a0 = *reinterpret_cast<const float4*>(qrow + 32 * h2 + kg * 8);
      float4 a1 = *reinterpret_cast<const float4*>(qrow + 32 * h2 + kg * 8 + 4);
      split8(a0, a1, ah[rk][h2], al[rk][h2]);
    }
  }
  __syncthreads();

  // per-row factors er_c = pi_c * exp2(L2E*(s*q^2 + 2s*(q.mu_c)))
  if (t < BM) {
    float pi0 = fminf(fmaxf(pi[0], 0.f), 1.f);
    float pi1 = fminf(fmaxf(pi[1], 0.f), 1.f);
    const float* qr = q + ((size_t)bh * L_ + row0 + t) * D_;
    float a0 = 0.f, a1 = 0.f, a2 = 0.f;
#pragma unroll
    for (int dq = 0; dq < 16; ++dq) {
      float4 qv = *reinterpret_cast<const float4*>(qr + 4 * dq);
      a0 += qv.x * qv.x + qv.y * qv.y + qv.z * qv.z + qv.w * qv.w;
      a1 += qv.x * S.muv[0][4*dq] + qv.y * S.muv[0][4*dq+1] +
            qv.z * S.muv[0][4*dq+2] + qv.w * S.muv[0][4*dq+3];
      a2 += qv.x * S.muv[1][4*dq] + qv.y * S.muv[1][4*dq+1] +
            qv.z * S.muv[1][4*dq+2] + qv.w * S.muv[1][4*dq+3];
    }
    S.er0[t] = pi0 * exp2f((s * a0 + 2.f * s * a1) * L2E);
    S.er1[t] = pi1 * exp2f((s * a0 + 2.f * s * a2) * L2E);
  }
  __syncthreads();

  float e0r[2][4], e1r[2][4];
#pragma unroll
  for (int rk = 0; rk < 2; ++rk)
#pragma unroll
    for (int reg = 0; reg < 4; ++reg) {
      e0r[rk][reg] = S.er0[rk * 16 + kg * 4 + reg];
      e1r[rk][reg] = S.er1[rk * 16 + kg * 4 + reg];
    }

  // ---------------- PASS A: row sums only (no stores, no row state) --------
  float rsum[2][4] = {{0.f, 0.f, 0.f, 0.f}, {0.f, 0.f, 0.f, 0.f}};
#pragma unroll 1
  for (int j = 0; j < NJ; ++j) {
    __syncthreads();
    float2 ec[2];
    if (USE_WS) {
#pragma unroll
      for (int i = 0; i < 4; ++i)
        GLL16(whb + (size_t)j * (BN * 8) + t + 256 * i, &S.kth[t + 256 * i]);
#pragma unroll
      for (int i = 0; i < 4; ++i)
        GLL16(wlb + (size_t)j * (BN * 8) + t + 256 * i, &S.ktl[t + 256 * i]);
#pragma unroll
      for (int n = 0; n < 2; ++n)
        ec[n] = ckb[j * BN + w * 32 + 16 * n + ci];
      __syncthreads();
    } else {
#pragma unroll
      for (int i = 0; i < 4; ++i) {
        int u = t + 256 * i;
        int col = u >> 3, gp = u & 7, g = gp ^ (col & 7);
        float4 x0 = kb4[(size_t)(j * BN + col) * 16 + 2 * g];
        float4 x1 = kb4[(size_t)(j * BN + col) * 16 + 2 * g + 1];
        short8 hi, lo;
        split8(x0, x1, hi, lo);
        S.kth[u] = hi;
        S.ktl[u] = lo;
      }
      if (t < BN) {
        const float* kc = kk + ((size_t)bh * L_ + j * BN + t) * D_;
        float s0 = 0.f, s1 = 0.f;
#pragma unroll
        for (int dq = 0; dq < 16; ++dq) {
          float4 kv = *reinterpret_cast<const float4*>(kc + 4 * dq);
          float a;
          a = kv.x - S.muv[0][4*dq];   s0 += a * a;
          a = kv.y - S.muv[0][4*dq+1]; s0 += a * a;
          a = kv.z - S.muv[0][4*dq+2]; s0 += a * a;
          a = kv.w - S.muv[0][4*dq+3]; s0 += a * a;
          a = kv.x - S.muv[1][4*dq];   s1 += a * a;
          a = kv.y - S.muv[1][4*dq+1]; s1 += a * a;
          a = kv.z - S.muv[1][4*dq+2]; s1 += a * a;
          a = kv.w - S.muv[1][4*dq+3]; s1 += a * a;
        }
        float neg = 1.0e6f * (1.0f - maskb[j * BN + t]);
        S.ckt[t] = make_float2(exp2f((s * s0 - neg) * L2E),
                               exp2f((s * s1 - neg) * L2E));
      }
      __syncthreads();
#pragma unroll
      for (int n = 0; n < 2; ++n) ec[n] = S.ckt[w * 32 + 16 * n + ci];
    }

#pragma unroll
    for (int n = 0; n < 2; ++n) {
      int base = (w * 32 + n * 16 + ci) * 8;
      short8 b0h = S.kth[base + (kg ^ x7)];
      short8 b1h = S.kth[base + ((4 + kg) ^ x7)];
      short8 b0l = S.ktl[base + (kg ^ x7)];
      short8 b1l = S.ktl[base + ((4 + kg) ^ x7)];
#pragma unroll
      for (int rk = 0; rk < 2; ++rk) {
        f4 acc = {0.f, 0.f, 0.f, 0.f};
        acc = MFMA16(ah[rk][0], b0h, acc);
        acc = MFMA16(ah[rk][1], b1h, acc);
        acc = MFMA16(ah[rk][0], b0l, acc);
        acc = MFMA16(ah[rk][1], b1l, acc);
        acc = MFMA16(al[rk][0], b0h, acc);
        acc = MFMA16(al[rk][1], b1h, acc);
#pragma unroll
        for (int reg = 0; reg < 4; ++reg) {
          float g2 = __builtin_amdgcn_exp2f(DDC * acc[reg]);
          float m  = fmaf(e0r[rk][reg], ec[n].x, e1r[rk][reg] * ec[n].y);
          rsum[rk][reg] = fmaf(g2, m, rsum[rk][reg]);
        }
      }
    }
  }

  // row-sum reduce: 16 col-lanes, then 4 waves; fold inv into row factors
#pragma unroll
  for (int rk = 0; rk < 2; ++rk)
#pragma unroll
    for (int reg = 0; reg < 4; ++reg) {
      float v = rsum[rk][reg];
      v += __shfl_xor(v, 1, 64);
      v += __shfl_xor(v, 2, 64);
      v += __shfl_xor(v, 4, 64);
      v += __shfl_xor(v, 8, 64);
      if (ci == 0) S.red[w][rk * 16 + kg * 4 + reg] = v;
    }
  __syncthreads();
#pragma unroll
  for (int rk = 0; rk < 2; ++rk)
#pragma unroll
    for (int reg = 0; reg < 4; ++reg) {
      int r = rk * 16 + kg * 4 + reg;
      float inv = 1.0f / (S.red[0][r] + S.red[1][r] + S.red[2][r] + S.red[3][r]);
      e0r[rk][reg] *= inv;
      e1r[rk][reg] *= inv;
    }

  // ---------------- PASS B: recompute + direct normalized store ------------
  // Descending j: tile NJ-1 is still resident in LDS from pass A.
  float* obr = out + ((size_t)bh * L_ + row0 + kg * 4) * L_ + w * 32 + ci;
#pragma unroll 1
  for (int jj = 0; jj < NJ; ++jj) {
    const int j = NJ - 1 - jj;
    float2 ec[2];
    if (jj != 0) {
      __syncthreads();
      if (USE_WS) {
#pragma unroll
        for (int i = 0; i < 4; ++i)
          GLL16(whb + (size_t)j * (BN * 8) + t + 256 * i, &S.kth[t + 256 * i]);
#pragma unroll
        for (int i = 0; i < 4; ++i)
          GLL16(wlb + (size_t)j * (BN * 8) + t + 256 * i, &S.ktl[t + 256 * i]);
#pragma unroll
        for (int n = 0; n < 2; ++n)
          ec[n] = ckb[j * BN + w * 32 + 16 * n + ci];
        __syncthreads();
      } else {
#pragma unroll
        for (int i = 0; i < 4; ++i) {
          int u = t + 256 * i;
          int col = u >> 3, gp = u & 7, g = gp ^ (col & 7);
          float4 x0 = kb4[(size_t)(j * BN + col) * 16 + 2 * g];
          float4 x1 = kb4[(size_t)(j * BN + col) * 16 + 2 * g + 1];
          short8 hi, lo;
          split8(x0, x1, hi, lo);
          S.kth[u] = hi;
          S.ktl[u] = lo;
        }
        if (t < BN) {
          const float* kc = kk + ((size_t)bh * L_ + j * BN + t) * D_;
          float s0 = 0.f, s1 = 0.f;
#pragma unroll
          for (int dq = 0; dq < 16; ++dq) {
            float4 kv = *reinterpret_cast<const float4*>(kc + 4 * dq);
            float a;
            a = kv.x - S.muv[0][4*dq];   s0 += a * a;
            a = kv.y - S.muv[0][4*dq+1]; s0 += a * a;
            a = kv.z - S.muv[0][4*dq+2]; s0 += a * a;
            a = kv.w - S.muv[0][4*dq+3]; s0 += a * a;
            a = kv.x - S.muv[1][4*dq];   s1 += a * a;
            a = kv.y - S.muv[1][4*dq+1]; s1 += a * a;
            a = kv.z - S.muv[1][4*dq+2]; s1 += a * a;
            a = kv.w - S.muv[1][4*dq+3]; s1 += a * a;
          }
          float neg = 1.0e6f * (1.0f - maskb[j * BN + t]);
          S.ckt[t] = make_float2(exp2f((s * s0 - neg) * L2E),
                                 exp2f((s * s1 - neg) * L2E));
        }
        __syncthreads();
#pragma unroll
        for (int n = 0; n < 2; ++n) ec[n] = S.ckt[w * 32 + 16 * n + ci];
      }
    } else {
      if (USE_WS) {
#pragma unroll
        for (int n = 0; n < 2; ++n)
          ec[n] = ckb[j * BN + w * 32 + 16 * n + ci];
      } else {
#pragma unroll
        for (int n = 0; n < 2; ++n) ec[n] = S.ckt[w * 32 + 16 * n + ci];
      }
    }

#pragma unroll
    for (int n = 0; n < 2; ++n) {
      int base = (w * 32 + n * 16 + ci) * 8;
      short8 b0h = S.kth[base + (kg ^ x7)];
      short8 b1h = S.kth[base + ((4 + kg) ^ x7)];
      short8 b0l = S.ktl[base + (kg ^ x7)];
      short8 b1l = S.ktl[base + ((4 + kg) ^ x7)];
#pragma unroll
      for (int rk = 0; rk < 2; ++rk) {
        f4 acc = {0.f, 0.f, 0.f, 0.f};
        acc = MFMA16(ah[rk][0], b0h, acc);
        acc = MFMA16(ah[rk][1], b1h, acc);
        acc = MFMA16(ah[rk][0], b0l, acc);
        acc = MFMA16(ah[rk][1], b1l, acc);
        acc = MFMA16(al[rk][0], b0h, acc);
        acc = MFMA16(al[rk][1], b1h, acc);
#pragma unroll
        for (int reg = 0; reg < 4; ++reg) {
          float g2 = __builtin_amdgcn_exp2f(DDC * acc[reg]);
          float m  = fmaf(e0r[rk][reg], ec[n].x, e1r[rk][reg] * ec[n].y);
          float p  = g2 * m;
          __builtin_nontemporal_store(
              p, obr + (size_t)(rk * 16 + reg) * L_ + (j * BN + n * 16));
        }
      }
    }
  }
}

extern "C" void kernel_launch(void* const* d_in, const int* in_sizes, int n_in,
                              void* d_out, int out_size, void* d_ws, size_t ws_size,
                              hipStream_t stream) {
  const float* q    = (const float*)d_in[0];
  const float* k    = (const float*)d_in[1];
  const float* mask = (const float*)d_in[2];
  const float* mu   = (const float*)d_in[3];
  const float* pi   = (const float*)d_in[4];
  float* out = (float*)d_out;

  const size_t smem     = sizeof(LdsT);
  const size_t ck_bytes = (size_t)B_ * H_ * L_ * sizeof(float2);       // 256 KB
  const size_t wp_bytes = (size_t)B_ * H_ * L_ * D_ * sizeof(short);   // 4 MB each
  const bool use_ws = (ws_size >= ck_bytes + 2 * wp_bytes) && (d_ws != nullptr);

  if (use_ws) {
    float2* ck = (float2*)d_ws;
    short8* wh = (short8*)((char*)d_ws + ck_bytes);
    short8* wl = (short8*)((char*)d_ws + ck_bytes + wp_bytes);
    (void)hipFuncSetAttribute(reinterpret_cast<const void*>(&mg_kernel<true>),
                              hipFuncAttributeMaxDynamicSharedMemorySize, (int)smem);
    prep_kernel<<<dim3(B_ * H_ * 8), dim3(256), 0, stream>>>(k, mask, mu, ck, wh, wl);
    mg_kernel<true><<<dim3(B_ * H_ * (L_ / BM)), dim3(256), smem, stream>>>(
        q, k, mask, mu, pi, ck, wh, wl, out);
  } else {
    (void)hipFuncSetAttribute(reinterpret_cast<const void*>(&mg_kernel<false>),
                              hipFuncAttributeMaxDynamicSharedMemorySize, (int)smem);
    mg_kernel<false><<<dim3(B_ * H_ * (L_ / BM)), dim3(256), smem, stream>>>(
        q, k, mask, mu, pi, nullptr, nullptr, nullptr, out);
  }
}

// Round 9
// 121.637 us; speedup vs baseline: 1.9782x; 1.0086x over previous
//
#include <hip/hip_runtime.h>
#include <math.h>

#define B_ 2
#define H_ 8
#define L_ 2048
#define D_ 64
#define BM 64          // rows per WG: waves 0-3 -> rows 0-31, waves 4-7 -> 32-63
#define BN 128         // cols per K tile
#define NJ (L_ / BN)   // 16 tiles
#define NT 512         // threads per WG
#define L2E 1.4426950408889634f

typedef __attribute__((ext_vector_type(8))) short short8;
typedef __attribute__((ext_vector_type(4))) float f4;

typedef __attribute__((address_space(3))) void lds_void_t;
typedef const __attribute__((address_space(1))) void gbl_void_t;
#define GLL16(gp, lp) __builtin_amdgcn_global_load_lds( \
    (gbl_void_t*)(gp), (lds_void_t*)(lp), 16, 0, 0)

#define MFMA16(a, b, c) __builtin_amdgcn_mfma_f32_16x16x32_bf16(a, b, c, 0, 0, 0)

struct LdsT {
  short8 kth[BN * 8];      // 16 KB; idx = col*8 + (slot ^ (col&7))
  short8 ktl[BN * 8];      // 16 KB
  float2 cka[L_];          // 16 KB: col factors for ALL columns (exp2'd)
  float  muv[2][D_];
  float  er0[BM], er1[BM]; // pi_c * exp2(rq_c) per row
  float  red[4][BM];
};

__device__ inline void split8(const float4& a0, const float4& a1,
                              short8& hi, short8& lo) {
  float xs[8] = {a0.x, a0.y, a0.z, a0.w, a1.x, a1.y, a1.z, a1.w};
#pragma unroll
  for (int e = 0; e < 8; ++e) {
    unsigned u  = __float_as_uint(xs[e]);
    unsigned hb = (u + 0x8000u) & 0xFFFF0000u;   // RN-ish bf16, residual exact
    float    r  = xs[e] - __uint_as_float(hb);
    unsigned lb = (__float_as_uint(r) + 0x8000u) >> 16;
    hi[e] = (short)(hb >> 16);
    lo[e] = (short)lb;
  }
}

// Precompute: col factors ec_c = exp2(L2E*(s*|k-mu_c|^2 - neg)), and K as
// pre-swizzled bf16 hi/lo: wh[(bh*L+c)*8+g'] = k[c][8*(g'^(c&7))..+7] (hi).
__global__ __launch_bounds__(256) void prep_kernel(
    const float* __restrict__ k, const float* __restrict__ mask,
    const float* __restrict__ mu, float2* __restrict__ ck,
    short8* __restrict__ wh, short8* __restrict__ wl)
{
  int bh = blockIdx.x >> 3;
  int c  = (blockIdx.x & 7) * 256 + threadIdx.x;
  int b  = bh >> 3, h = bh & 7;
  const float s = -0.0625f;  // -0.5 / sqrt(64)
  const float* kp  = k  + ((size_t)bh * L_ + c) * D_;
  const float* mu0 = mu + (size_t)h * D_;
  const float* mu1 = mu + (size_t)(H_ * D_) + (size_t)h * D_;
  float x[D_];
#pragma unroll
  for (int d = 0; d < D_; d += 4)
    *reinterpret_cast<float4*>(&x[d]) = *reinterpret_cast<const float4*>(kp + d);
  float s0 = 0.f, s1 = 0.f;
#pragma unroll
  for (int d = 0; d < D_; ++d) {
    float a = x[d] - mu0[d]; s0 += a * a;
    float bb = x[d] - mu1[d]; s1 += bb * bb;
  }
  float neg = 1.0e6f * (1.0f - mask[(size_t)b * L_ + c]);
  ck[(size_t)bh * L_ + c] = make_float2(exp2f((s * s0 - neg) * L2E),
                                        exp2f((s * s1 - neg) * L2E));
#pragma unroll
  for (int gp = 0; gp < 8; ++gp) {
    int g = gp ^ (c & 7);
    short8 hi, lo;
    split8(*reinterpret_cast<const float4*>(&x[8 * g]),
           *reinterpret_cast<const float4*>(&x[8 * g + 4]), hi, lo);
    size_t idx = ((size_t)bh * L_ + c) * 8 + gp;
    wh[idx] = hi;
    wl[idx] = lo;
  }
}

template <bool USE_WS>
__global__ __launch_bounds__(NT, 2) void mg_kernel(
    const float* __restrict__ q, const float* __restrict__ kk,
    const float* __restrict__ mask, const float* __restrict__ mu,
    const float* __restrict__ pi, const float2* __restrict__ ckw,
    const short8* __restrict__ wh, const short8* __restrict__ wl,
    float* __restrict__ out)
{
  extern __shared__ __align__(16) char smem_raw[];
  LdsT& S = *reinterpret_cast<LdsT*>(smem_raw);
  const int t = threadIdx.x;
  int bid = blockIdx.x;
  int vwg = (bid & 7) * 64 + (bid >> 3);   // XCD-chunked, bijective (512%8==0)
  int bh  = vwg >> 5;
  int rb  = vwg & 31;
  int b = bh >> 3, h = bh & 7;
  int row0 = rb * BM;

  const int w  = t >> 6;          // wave 0..7
  const int ln = t & 63;
  const int ci = ln & 15;         // col lane / A-row lane
  const int kg = ln >> 4;         // k-group lane
  const int x7 = ci & 7;
  const int wc = w & 3;           // col chunk 0..3
  const int wr = (w >> 2) * 32;   // row-block base 0 or 32

  const float s   = -0.0625f;
  const float DDC = 0.125f * L2E;   // -2s * log2e

  const float*  maskb = mask + (size_t)b * L_;
  const float2* ckb   = ckw + (size_t)bh * L_;
  const float4* kb4   = (const float4*)(kk + (size_t)bh * L_ * D_);
  const short8* whb   = wh + (size_t)bh * (L_ * 8);
  const short8* wlb   = wl + (size_t)bh * (L_ * 8);

  if (t < 2 * D_)
    S.muv[t >> 6][t & 63] =
        mu[(size_t)(t >> 6) * (H_ * D_) + (size_t)h * D_ + (t & 63)];

  // col factors for all 2048 cols staged once (USE_WS path)
  if (USE_WS) {
#pragma unroll
    for (int i = 0; i < 4; ++i) {
      int u = t + NT * i;
      S.cka[u] = ckb[u];
    }
  }

  // A-fragments: 2 row-blocks of 16 rows each (split bf16)
  short8 ah[2][2], al[2][2];
#pragma unroll
  for (int rk = 0; rk < 2; ++rk) {
    const float* qrow = q + ((size_t)bh * L_ + row0 + wr + rk * 16 + ci) * D_;
#pragma unroll
    for (int h2 = 0; h2 < 2; ++h2) {
      float4 a0 = *reinterpret_cast<const float4*>(qrow + 32 * h2 + kg * 8);
      float4 a1 = *reinterpret_cast<const float4*>(qrow + 32 * h2 + kg * 8 + 4);
      split8(a0, a1, ah[rk][h2], al[rk][h2]);
    }
  }
  __syncthreads();

  // per-row factors er_c = pi_c * exp2(L2E*(s*q^2 + 2s*(q.mu_c)))
  if (t < BM) {
    float pi0 = fminf(fmaxf(pi[0], 0.f), 1.f);
    float pi1 = fminf(fmaxf(pi[1], 0.f), 1.f);
    const float* qr = q + ((size_t)bh * L_ + row0 + t) * D_;
    float a0 = 0.f, a1 = 0.f, a2 = 0.f;
#pragma unroll
    for (int dq = 0; dq < 16; ++dq) {
      float4 qv = *reinterpret_cast<const float4*>(qr + 4 * dq);
      a0 += qv.x * qv.x + qv.y * qv.y + qv.z * qv.z + qv.w * qv.w;
      a1 += qv.x * S.muv[0][4*dq] + qv.y * S.muv[0][4*dq+1] +
            qv.z * S.muv[0][4*dq+2] + qv.w * S.muv[0][4*dq+3];
      a2 += qv.x * S.muv[1][4*dq] + qv.y * S.muv[1][4*dq+1] +
            qv.z * S.muv[1][4*dq+2] + qv.w * S.muv[1][4*dq+3];
    }
    S.er0[t] = pi0 * exp2f((s * a0 + 2.f * s * a1) * L2E);
    S.er1[t] = pi1 * exp2f((s * a0 + 2.f * s * a2) * L2E);
  }
  __syncthreads();

  float e0r[2][4], e1r[2][4];
#pragma unroll
  for (int rk = 0; rk < 2; ++rk)
#pragma unroll
    for (int reg = 0; reg < 4; ++reg) {
      e0r[rk][reg] = S.er0[wr + rk * 16 + kg * 4 + reg];
      e1r[rk][reg] = S.er1[wr + rk * 16 + kg * 4 + reg];
    }

  // stage tile j into the single K buffer (R7-proven: caller brackets with
  // __syncthreads before and after)
  auto STAGE = [&](int j) {
    if (USE_WS) {
#pragma unroll
      for (int i = 0; i < 2; ++i)
        GLL16(whb + (size_t)j * (BN * 8) + t + NT * i, &S.kth[t + NT * i]);
#pragma unroll
      for (int i = 0; i < 2; ++i)
        GLL16(wlb + (size_t)j * (BN * 8) + t + NT * i, &S.ktl[t + NT * i]);
    } else {
#pragma unroll
      for (int i = 0; i < 2; ++i) {
        int u = t + NT * i;
        int col = u >> 3, gp = u & 7, g = gp ^ (col & 7);
        float4 x0 = kb4[(size_t)(j * BN + col) * 16 + 2 * g];
        float4 x1 = kb4[(size_t)(j * BN + col) * 16 + 2 * g + 1];
        short8 hi, lo;
        split8(x0, x1, hi, lo);
        S.kth[u] = hi;
        S.ktl[u] = lo;
      }
      if (t < BN) {
        const float* kc = kk + ((size_t)bh * L_ + j * BN + t) * D_;
        float s0 = 0.f, s1 = 0.f;
#pragma unroll
        for (int dq = 0; dq < 16; ++dq) {
          float4 kv = *reinterpret_cast<const float4*>(kc + 4 * dq);
          float a;
          a = kv.x - S.muv[0][4*dq];   s0 += a * a;
          a = kv.y - S.muv[0][4*dq+1]; s0 += a * a;
          a = kv.z - S.muv[0][4*dq+2]; s0 += a * a;
          a = kv.w - S.muv[0][4*dq+3]; s0 += a * a;
          a = kv.x - S.muv[1][4*dq];   s1 += a * a;
          a = kv.y - S.muv[1][4*dq+1]; s1 += a * a;
          a = kv.z - S.muv[1][4*dq+2]; s1 += a * a;
          a = kv.w - S.muv[1][4*dq+3]; s1 += a * a;
        }
        float neg = 1.0e6f * (1.0f - maskb[j * BN + t]);
        S.cka[j * BN + t] = make_float2(exp2f((s * s0 - neg) * L2E),
                                        exp2f((s * s1 - neg) * L2E));
      }
    }
  };

  // ---------------- PASS A: row sums only ----------------------------------
  float rsum[2][4] = {{0.f, 0.f, 0.f, 0.f}, {0.f, 0.f, 0.f, 0.f}};
#pragma unroll 1
  for (int j = 0; j < NJ; ++j) {
    __syncthreads();   // previous tile's reads done -> buffer writable
    STAGE(j);
    __syncthreads();   // staged data visible (vmcnt drained by barrier)
    float2 ec[2];
#pragma unroll
    for (int n = 0; n < 2; ++n)
      ec[n] = S.cka[j * BN + wc * 32 + 16 * n + ci];
#pragma unroll
    for (int n = 0; n < 2; ++n) {
      int base = (wc * 32 + n * 16 + ci) * 8;
      short8 b0h = S.kth[base + (kg ^ x7)];
      short8 b1h = S.kth[base + ((4 + kg) ^ x7)];
      short8 b0l = S.ktl[base + (kg ^ x7)];
      short8 b1l = S.ktl[base + ((4 + kg) ^ x7)];
#pragma unroll
      for (int rk = 0; rk < 2; ++rk) {
        f4 acc = {0.f, 0.f, 0.f, 0.f};
        acc = MFMA16(ah[rk][0], b0h, acc);
        acc = MFMA16(ah[rk][1], b1h, acc);
        acc = MFMA16(ah[rk][0], b0l, acc);
        acc = MFMA16(ah[rk][1], b1l, acc);
        acc = MFMA16(al[rk][0], b0h, acc);
        acc = MFMA16(al[rk][1], b1h, acc);
#pragma unroll
        for (int reg = 0; reg < 4; ++reg) {
          float g2 = __builtin_amdgcn_exp2f(DDC * acc[reg]);
          float m  = fmaf(e0r[rk][reg], ec[n].x, e1r[rk][reg] * ec[n].y);
          rsum[rk][reg] = fmaf(g2, m, rsum[rk][reg]);
        }
      }
    }
  }

  // row-sum reduce: 16 col-lanes, then 4 col-waves; fold inv into row factors
#pragma unroll
  for (int rk = 0; rk < 2; ++rk)
#pragma unroll
    for (int reg = 0; reg < 4; ++reg) {
      float v = rsum[rk][reg];
      v += __shfl_xor(v, 1, 64);
      v += __shfl_xor(v, 2, 64);
      v += __shfl_xor(v, 4, 64);
      v += __shfl_xor(v, 8, 64);
      if (ci == 0) S.red[wc][wr + rk * 16 + kg * 4 + reg] = v;
    }
  __syncthreads();
#pragma unroll
  for (int rk = 0; rk < 2; ++rk)
#pragma unroll
    for (int reg = 0; reg < 4; ++reg) {
      int r = wr + rk * 16 + kg * 4 + reg;
      float inv = 1.0f / (S.red[0][r] + S.red[1][r] + S.red[2][r] + S.red[3][r]);
      e0r[rk][reg] *= inv;
      e1r[rk][reg] *= inv;
    }

  // ---------------- PASS B: recompute + direct normalized store ------------
  // Descending j: tile NJ-1 is still resident in LDS from pass A.
  float* ob = out + ((size_t)bh * L_ + row0 + wr + kg * 4) * L_ + wc * 32 + ci;
#pragma unroll 1
  for (int jj = 0; jj < NJ; ++jj) {
    const int j = NJ - 1 - jj;
    if (jj != 0) {
      __syncthreads();   // previous tile's reads done
      STAGE(j);
      __syncthreads();   // staged data visible
    }
    float2 ec[2];
#pragma unroll
    for (int n = 0; n < 2; ++n)
      ec[n] = S.cka[j * BN + wc * 32 + 16 * n + ci];
#pragma unroll
    for (int n = 0; n < 2; ++n) {
      int base = (wc * 32 + n * 16 + ci) * 8;
      short8 b0h = S.kth[base + (kg ^ x7)];
      short8 b1h = S.kth[base + ((4 + kg) ^ x7)];
      short8 b0l = S.ktl[base + (kg ^ x7)];
      short8 b1l = S.ktl[base + ((4 + kg) ^ x7)];
#pragma unroll
      for (int rk = 0; rk < 2; ++rk) {
        f4 acc = {0.f, 0.f, 0.f, 0.f};
        acc = MFMA16(ah[rk][0], b0h, acc);
        acc = MFMA16(ah[rk][1], b1h, acc);
        acc = MFMA16(ah[rk][0], b0l, acc);
        acc = MFMA16(ah[rk][1], b1l, acc);
        acc = MFMA16(al[rk][0], b0h, acc);
        acc = MFMA16(al[rk][1], b1h, acc);
#pragma unroll
        for (int reg = 0; reg < 4; ++reg) {
          float g2 = __builtin_amdgcn_exp2f(DDC * acc[reg]);
          float m  = fmaf(e0r[rk][reg], ec[n].x, e1r[rk][reg] * ec[n].y);
          float p  = g2 * m;
          __builtin_nontemporal_store(
              p, ob + (size_t)(rk * 16 + reg) * L_ + (j * BN + n * 16));
        }
      }
    }
  }
}

extern "C" void kernel_launch(void* const* d_in, const int* in_sizes, int n_in,
                              void* d_out, int out_size, void* d_ws, size_t ws_size,
                              hipStream_t stream) {
  const float* q    = (const float*)d_in[0];
  const float* k    = (const float*)d_in[1];
  const float* mask = (const float*)d_in[2];
  const float* mu   = (const float*)d_in[3];
  const float* pi   = (const float*)d_in[4];
  float* out = (float*)d_out;

  const size_t smem     = sizeof(LdsT);
  const size_t ck_bytes = (size_t)B_ * H_ * L_ * sizeof(float2);       // 256 KB
  const size_t wp_bytes = (size_t)B_ * H_ * L_ * D_ * sizeof(short);   // 4 MB each
  const bool use_ws = (ws_size >= ck_bytes + 2 * wp_bytes) && (d_ws != nullptr);

  if (use_ws) {
    float2* ck = (float2*)d_ws;
    short8* wh = (short8*)((char*)d_ws + ck_bytes);
    short8* wl = (short8*)((char*)d_ws + ck_bytes + wp_bytes);
    (void)hipFuncSetAttribute(reinterpret_cast<const void*>(&mg_kernel<true>),
                              hipFuncAttributeMaxDynamicSharedMemorySize, (int)smem);
    prep_kernel<<<dim3(B_ * H_ * 8), dim3(256), 0, stream>>>(k, mask, mu, ck, wh, wl);
    mg_kernel<true><<<dim3(B_ * H_ * (L_ / BM)), dim3(NT), smem, stream>>>(
        q, k, mask, mu, pi, ck, wh, wl, out);
  } else {
    (void)hipFuncSetAttribute(reinterpret_cast<const void*>(&mg_kernel<false>),
                              hipFuncAttributeMaxDynamicSharedMemorySize, (int)smem);
    mg_kernel<false><<<dim3(B_ * H_ * (L_ / BM)), dim3(NT), smem, stream>>>(
        q, k, mask, mu, pi, nullptr, nullptr, nullptr, out);
  }
}

// Round 10
// 113.951 us; speedup vs baseline: 2.1116x; 1.0674x over previous
//
#include <hip/hip_runtime.h>
#include <math.h>

#define B_ 2
#define H_ 8
#define L_ 2048
#define D_ 64
#define BM 32          // rows per WG: waves 0-3 -> rows 0-15, waves 4-7 -> 16-31
#define BN 128         // cols per K tile
#define NJ (L_ / BN)   // 16 tiles
#define NT 512         // threads per WG
#define L2E 1.4426950408889634f

typedef _Float16 half8 __attribute__((ext_vector_type(8)));
typedef __attribute__((ext_vector_type(4))) float f4;

typedef __attribute__((address_space(3))) void lds_void_t;
typedef const __attribute__((address_space(1))) void gbl_void_t;
#define GLL16(gp, lp) __builtin_amdgcn_global_load_lds( \
    (gbl_void_t*)(gp), (lds_void_t*)(lp), 16, 0, 0)

#define MFMA16F(a, b, c) __builtin_amdgcn_mfma_f32_16x16x32_f16(a, b, c, 0, 0, 0)

struct LdsT {
  half8  kth[BN * 8];      // 16 KB; idx = col*8 + (slot ^ (col&7)), fp16 K
  float2 cka[L_];          // 16 KB: col factors for ALL columns (exp2'd)
  float  muv[2][D_];       // 512 B
  float  er0[BM], er1[BM]; // pi_c * exp2(rq_c) per row
  float  red[4][BM];
};

__device__ inline half8 cvt8(const float4& a0, const float4& a1) {
  half8 r;
  r[0] = (_Float16)a0.x; r[1] = (_Float16)a0.y;
  r[2] = (_Float16)a0.z; r[3] = (_Float16)a0.w;
  r[4] = (_Float16)a1.x; r[5] = (_Float16)a1.y;
  r[6] = (_Float16)a1.z; r[7] = (_Float16)a1.w;
  return r;
}

// Precompute: col factors ec_c = exp2(L2E*(s*|k-mu_c|^2 - neg)), and K as
// pre-swizzled fp16: wh[(bh*L+c)*8+g'] = fp16(k[c][8*(g'^(c&7)) .. +7]).
__global__ __launch_bounds__(256) void prep_kernel(
    const float* __restrict__ k, const float* __restrict__ mask,
    const float* __restrict__ mu, float2* __restrict__ ck,
    half8* __restrict__ wh)
{
  int bh = blockIdx.x >> 3;
  int c  = (blockIdx.x & 7) * 256 + threadIdx.x;
  int b  = bh >> 3, h = bh & 7;
  const float s = -0.0625f;  // -0.5 / sqrt(64)
  const float* kp  = k  + ((size_t)bh * L_ + c) * D_;
  const float* mu0 = mu + (size_t)h * D_;
  const float* mu1 = mu + (size_t)(H_ * D_) + (size_t)h * D_;
  float x[D_];
#pragma unroll
  for (int d = 0; d < D_; d += 4)
    *reinterpret_cast<float4*>(&x[d]) = *reinterpret_cast<const float4*>(kp + d);
  float s0 = 0.f, s1 = 0.f;
#pragma unroll
  for (int d = 0; d < D_; ++d) {
    float a = x[d] - mu0[d]; s0 += a * a;
    float bb = x[d] - mu1[d]; s1 += bb * bb;
  }
  float neg = 1.0e6f * (1.0f - mask[(size_t)b * L_ + c]);
  ck[(size_t)bh * L_ + c] = make_float2(exp2f((s * s0 - neg) * L2E),
                                        exp2f((s * s1 - neg) * L2E));
#pragma unroll
  for (int gp = 0; gp < 8; ++gp) {
    int g = gp ^ (c & 7);
    wh[((size_t)bh * L_ + c) * 8 + gp] =
        cvt8(*reinterpret_cast<const float4*>(&x[8 * g]),
             *reinterpret_cast<const float4*>(&x[8 * g + 4]));
  }
}

template <bool USE_WS>
__global__ __launch_bounds__(NT, 8) void mg_kernel(
    const float* __restrict__ q, const float* __restrict__ kk,
    const float* __restrict__ mask, const float* __restrict__ mu,
    const float* __restrict__ pi, const float2* __restrict__ ckw,
    const half8* __restrict__ wh, float* __restrict__ out)
{
  extern __shared__ __align__(16) char smem_raw[];
  LdsT& S = *reinterpret_cast<LdsT*>(smem_raw);
  const int t = threadIdx.x;
  int bid = blockIdx.x;
  int vwg = (bid & 7) * 128 + (bid >> 3);   // XCD-chunked, bijective (1024%8==0)
  int bh  = vwg >> 6;
  int rb  = vwg & 63;
  int b = bh >> 3, h = bh & 7;
  int row0 = rb * BM;

  const int w  = t >> 6;          // wave 0..7
  const int ln = t & 63;
  const int ci = ln & 15;         // col lane / A-row lane
  const int kg = ln >> 4;         // k-group lane
  const int x7 = ci & 7;
  const int wc = w & 3;           // col chunk 0..3
  const int wr = (w >> 2) * 16;   // row-block base 0 or 16

  const float s   = -0.0625f;
  const float DDC = 0.125f * L2E;   // -2s * log2e

  const float*  maskb = mask + (size_t)b * L_;
  const float2* ckb   = ckw + (size_t)bh * L_;
  const float4* kb4   = (const float4*)(kk + (size_t)bh * L_ * D_);
  const half8*  whb   = wh + (size_t)bh * (L_ * 8);

  if (t < 2 * D_)
    S.muv[t >> 6][t & 63] =
        mu[(size_t)(t >> 6) * (H_ * D_) + (size_t)h * D_ + (t & 63)];

  // col factors for all 2048 cols staged once (USE_WS path)
  if (USE_WS) {
#pragma unroll
    for (int i = 0; i < 4; ++i) {
      int u = t + NT * i;
      S.cka[u] = ckb[u];
    }
  }

  // A-fragments: 1 row-block of 16 rows, fp16 (single precision level)
  half8 ah[2];
  {
    const float* qrow = q + ((size_t)bh * L_ + row0 + wr + ci) * D_;
#pragma unroll
    for (int h2 = 0; h2 < 2; ++h2) {
      float4 a0 = *reinterpret_cast<const float4*>(qrow + 32 * h2 + kg * 8);
      float4 a1 = *reinterpret_cast<const float4*>(qrow + 32 * h2 + kg * 8 + 4);
      ah[h2] = cvt8(a0, a1);
    }
  }
  __syncthreads();

  // per-row factors er_c = pi_c * exp2(L2E*(s*q^2 + 2s*(q.mu_c)))
  if (t < BM) {
    float pi0 = fminf(fmaxf(pi[0], 0.f), 1.f);
    float pi1 = fminf(fmaxf(pi[1], 0.f), 1.f);
    const float* qr = q + ((size_t)bh * L_ + row0 + t) * D_;
    float a0 = 0.f, a1 = 0.f, a2 = 0.f;
#pragma unroll
    for (int dq = 0; dq < 16; ++dq) {
      float4 qv = *reinterpret_cast<const float4*>(qr + 4 * dq);
      a0 += qv.x * qv.x + qv.y * qv.y + qv.z * qv.z + qv.w * qv.w;
      a1 += qv.x * S.muv[0][4*dq] + qv.y * S.muv[0][4*dq+1] +
            qv.z * S.muv[0][4*dq+2] + qv.w * S.muv[0][4*dq+3];
      a2 += qv.x * S.muv[1][4*dq] + qv.y * S.muv[1][4*dq+1] +
            qv.z * S.muv[1][4*dq+2] + qv.w * S.muv[1][4*dq+3];
    }
    S.er0[t] = pi0 * exp2f((s * a0 + 2.f * s * a1) * L2E);
    S.er1[t] = pi1 * exp2f((s * a0 + 2.f * s * a2) * L2E);
  }
  __syncthreads();

  float e0r[4], e1r[4];
#pragma unroll
  for (int reg = 0; reg < 4; ++reg) {
    e0r[reg] = S.er0[wr + kg * 4 + reg];
    e1r[reg] = S.er1[wr + kg * 4 + reg];
  }

  // stage tile j (caller brackets with __syncthreads before and after)
  auto STAGE = [&](int j) {
    if (USE_WS) {
#pragma unroll
      for (int i = 0; i < 2; ++i)
        GLL16(whb + (size_t)j * (BN * 8) + t + NT * i, &S.kth[t + NT * i]);
    } else {
#pragma unroll
      for (int i = 0; i < 2; ++i) {
        int u = t + NT * i;
        int col = u >> 3, gp = u & 7, g = gp ^ (col & 7);
        float4 x0 = kb4[(size_t)(j * BN + col) * 16 + 2 * g];
        float4 x1 = kb4[(size_t)(j * BN + col) * 16 + 2 * g + 1];
        S.kth[u] = cvt8(x0, x1);
      }
      if (t < BN) {
        const float* kc = kk + ((size_t)bh * L_ + j * BN + t) * D_;
        float s0 = 0.f, s1 = 0.f;
#pragma unroll
        for (int dq = 0; dq < 16; ++dq) {
          float4 kv = *reinterpret_cast<const float4*>(kc + 4 * dq);
          float a;
          a = kv.x - S.muv[0][4*dq];   s0 += a * a;
          a = kv.y - S.muv[0][4*dq+1]; s0 += a * a;
          a = kv.z - S.muv[0][4*dq+2]; s0 += a * a;
          a = kv.w - S.muv[0][4*dq+3]; s0 += a * a;
          a = kv.x - S.muv[1][4*dq];   s1 += a * a;
          a = kv.y - S.muv[1][4*dq+1]; s1 += a * a;
          a = kv.z - S.muv[1][4*dq+2]; s1 += a * a;
          a = kv.w - S.muv[1][4*dq+3]; s1 += a * a;
        }
        float neg = 1.0e6f * (1.0f - maskb[j * BN + t]);
        S.cka[j * BN + t] = make_float2(exp2f((s * s0 - neg) * L2E),
                                        exp2f((s * s1 - neg) * L2E));
      }
    }
  };

  // ---------------- PASS A: row sums only ----------------------------------
  float rsum[4] = {0.f, 0.f, 0.f, 0.f};
#pragma unroll 1
  for (int j = 0; j < NJ; ++j) {
    __syncthreads();   // previous tile's reads done -> buffer writable
    STAGE(j);
    __syncthreads();   // staged data visible
    float2 ec[2];
#pragma unroll
    for (int n = 0; n < 2; ++n)
      ec[n] = S.cka[j * BN + wc * 32 + 16 * n + ci];
#pragma unroll
    for (int n = 0; n < 2; ++n) {
      int base = (wc * 32 + n * 16 + ci) * 8;
      half8 b0 = S.kth[base + (kg ^ x7)];
      half8 b1 = S.kth[base + ((4 + kg) ^ x7)];
      f4 acc = {0.f, 0.f, 0.f, 0.f};
      acc = MFMA16F(ah[0], b0, acc);
      acc = MFMA16F(ah[1], b1, acc);
#pragma unroll
      for (int reg = 0; reg < 4; ++reg) {
        float g2 = __builtin_amdgcn_exp2f(DDC * acc[reg]);
        float m  = fmaf(e0r[reg], ec[n].x, e1r[reg] * ec[n].y);
        rsum[reg] = fmaf(g2, m, rsum[reg]);
      }
    }
  }

  // row-sum reduce: 16 col-lanes, then 4 col-waves; fold inv into row factors
#pragma unroll
  for (int reg = 0; reg < 4; ++reg) {
    float v = rsum[reg];
    v += __shfl_xor(v, 1, 64);
    v += __shfl_xor(v, 2, 64);
    v += __shfl_xor(v, 4, 64);
    v += __shfl_xor(v, 8, 64);
    if (ci == 0) S.red[wc][wr + kg * 4 + reg] = v;
  }
  __syncthreads();
#pragma unroll
  for (int reg = 0; reg < 4; ++reg) {
    int r = wr + kg * 4 + reg;
    float inv = 1.0f / (S.red[0][r] + S.red[1][r] + S.red[2][r] + S.red[3][r]);
    e0r[reg] *= inv;
    e1r[reg] *= inv;
  }

  // ---------------- PASS B: recompute + direct normalized store ------------
  // Descending j: tile NJ-1 is still resident in LDS from pass A.
  float* ob = out + ((size_t)bh * L_ + row0 + wr + kg * 4) * L_ + wc * 32 + ci;
#pragma unroll 1
  for (int jj = 0; jj < NJ; ++jj) {
    const int j = NJ - 1 - jj;
    if (jj != 0) {
      __syncthreads();   // previous tile's reads done
      STAGE(j);
      __syncthreads();   // staged data visible
    }
    float2 ec[2];
#pragma unroll
    for (int n = 0; n < 2; ++n)
      ec[n] = S.cka[j * BN + wc * 32 + 16 * n + ci];
#pragma unroll
    for (int n = 0; n < 2; ++n) {
      int base = (wc * 32 + n * 16 + ci) * 8;
      half8 b0 = S.kth[base + (kg ^ x7)];
      half8 b1 = S.kth[base + ((4 + kg) ^ x7)];
      f4 acc = {0.f, 0.f, 0.f, 0.f};
      acc = MFMA16F(ah[0], b0, acc);
      acc = MFMA16F(ah[1], b1, acc);
#pragma unroll
      for (int reg = 0; reg < 4; ++reg) {
        float g2 = __builtin_amdgcn_exp2f(DDC * acc[reg]);
        float m  = fmaf(e0r[reg], ec[n].x, e1r[reg] * ec[n].y);
        float p  = g2 * m;
        __builtin_nontemporal_store(
            p, ob + (size_t)reg * L_ + (j * BN + n * 16));
      }
    }
  }
}

extern "C" void kernel_launch(void* const* d_in, const int* in_sizes, int n_in,
                              void* d_out, int out_size, void* d_ws, size_t ws_size,
                              hipStream_t stream) {
  const float* q    = (const float*)d_in[0];
  const float* k    = (const float*)d_in[1];
  const float* mask = (const float*)d_in[2];
  const float* mu   = (const float*)d_in[3];
  const float* pi   = (const float*)d_in[4];
  float* out = (float*)d_out;

  const size_t smem     = sizeof(LdsT);
  const size_t ck_bytes = (size_t)B_ * H_ * L_ * sizeof(float2);       // 256 KB
  const size_t wp_bytes = (size_t)B_ * H_ * L_ * D_ * sizeof(short);   // 4 MB (fp16)
  const bool use_ws = (ws_size >= ck_bytes + wp_bytes) && (d_ws != nullptr);

  if (use_ws) {
    float2* ck = (float2*)d_ws;
    half8*  wh = (half8*)((char*)d_ws + ck_bytes);
    (void)hipFuncSetAttribute(reinterpret_cast<const void*>(&mg_kernel<true>),
                              hipFuncAttributeMaxDynamicSharedMemorySize, (int)smem);
    prep_kernel<<<dim3(B_ * H_ * 8), dim3(256), 0, stream>>>(k, mask, mu, ck, wh);
    mg_kernel<true><<<dim3(B_ * H_ * (L_ / BM)), dim3(NT), smem, stream>>>(
        q, k, mask, mu, pi, ck, wh, out);
  } else {
    (void)hipFuncSetAttribute(reinterpret_cast<const void*>(&mg_kernel<false>),
                              hipFuncAttributeMaxDynamicSharedMemorySize, (int)smem);
    mg_kernel<false><<<dim3(B_ * H_ * (L_ / BM)), dim3(NT), smem, stream>>>(
        q, k, mask, mu, pi, nullptr, nullptr, out);
  }
}